// Round 1
// baseline (598.142 us; speedup 1.0000x reference)
//
#include <hip/hip_runtime.h>
#include <hip/hip_bf16.h>
#include <cstdint>

#define D_MODEL 256
#define NHEADS 8
#define DK 32

typedef float f32x4 __attribute__((ext_vector_type(4)));
typedef __bf16 bf16x8 __attribute__((ext_vector_type(8)));

__device__ __forceinline__ unsigned short f2bf_rne(float f) {
    unsigned int u = __float_as_uint(f);
    u += 0x7FFF + ((u >> 16) & 1);
    return (unsigned short)(u >> 16);
}
__device__ __forceinline__ float bf2f(unsigned short h) {
    return __uint_as_float(((unsigned int)h) << 16);
}

// ---------------- weight fp32 -> bf16 conversion (all 4 weights) ----------------
__global__ void conv_weights(const float* __restrict__ Wq, const float* __restrict__ Wk,
                             const float* __restrict__ Wv, const float* __restrict__ Wo,
                             unsigned short* __restrict__ out) {
    int i = blockIdx.x * blockDim.x + threadIdx.x;
    if (i < D_MODEL * D_MODEL) {
        out[i]                         = f2bf_rne(Wq[i]);
        out[D_MODEL * D_MODEL + i]     = f2bf_rne(Wk[i]);
        out[2 * D_MODEL * D_MODEL + i] = f2bf_rne(Wv[i]);
        out[3 * D_MODEL * D_MODEL + i] = f2bf_rne(Wo[i]);
    }
}

// ---------------- GEMM: out[M,256] = A[M,256] @ W[256,256]^T + bias -------------
// BM=64 rows/block, BN=256 (full width; wave w covers cols 64w..64w+63).
// A: fp32 in global, converted to bf16 in-register. W: bf16 (L2-resident).
// MFMA 16x16x32 bf16. A-frag: A[m=lane&15][k=quad*8+j]; B-frag: W[n=lane&15][k=quad*8+j];
// D: col=lane&15, row=quad*4+reg.
template <int OUT_BF16>
__global__ __launch_bounds__(256, 2) void gemm_proj(
    const float* __restrict__ A, const unsigned short* __restrict__ Wb,
    const float* __restrict__ bias, void* __restrict__ outp, int M)
{
    const int lane  = threadIdx.x & 63;
    const int wave  = threadIdx.x >> 6;
    const int m0    = blockIdx.x * 64;
    const int nbase = wave * 64;
    const int mrow  = lane & 15;
    const int quad  = lane >> 4;

    f32x4 acc[4][4] = {};

    int arow[4];
#pragma unroll
    for (int mi = 0; mi < 4; ++mi) {
        int r = m0 + mi * 16 + mrow;
        arow[mi] = (r < M) ? r : (M - 1);   // clamp; stores are guarded
    }

#pragma unroll
    for (int kk = 0; kk < 8; ++kk) {
        const int kof = kk * 32 + quad * 8;
        bf16x8 afr[4];
#pragma unroll
        for (int mi = 0; mi < 4; ++mi) {
            const float* ap = A + (size_t)arow[mi] * D_MODEL + kof;
            float4 x0 = *(const float4*)ap;
            float4 x1 = *(const float4*)(ap + 4);
            bf16x8 t;
            t[0] = (__bf16)x0.x; t[1] = (__bf16)x0.y; t[2] = (__bf16)x0.z; t[3] = (__bf16)x0.w;
            t[4] = (__bf16)x1.x; t[5] = (__bf16)x1.y; t[6] = (__bf16)x1.z; t[7] = (__bf16)x1.w;
            afr[mi] = t;
        }
        bf16x8 bfr[4];
#pragma unroll
        for (int ni = 0; ni < 4; ++ni) {
            const unsigned short* bp = Wb + (size_t)(nbase + ni * 16 + mrow) * D_MODEL + kof;
            bfr[ni] = *(const bf16x8*)bp;
        }
#pragma unroll
        for (int mi = 0; mi < 4; ++mi)
#pragma unroll
            for (int ni = 0; ni < 4; ++ni)
                acc[mi][ni] = __builtin_amdgcn_mfma_f32_16x16x32_bf16(
                    afr[mi], bfr[ni], acc[mi][ni], 0, 0, 0);
    }

#pragma unroll
    for (int ni = 0; ni < 4; ++ni) {
        const int col = nbase + ni * 16 + mrow;
        const float bv = bias[col];
#pragma unroll
        for (int mi = 0; mi < 4; ++mi) {
#pragma unroll
            for (int r = 0; r < 4; ++r) {
                const int row = m0 + mi * 16 + quad * 4 + r;
                if (row < M) {
                    float val = acc[mi][ni][r] + bv;
                    if (OUT_BF16)
                        ((unsigned short*)outp)[(size_t)row * D_MODEL + col] = f2bf_rne(val);
                    else
                        ((float*)outp)[(size_t)row * D_MODEL + col] = val;
                }
            }
        }
    }
}

// ---------------- CSR construction ----------------
__global__ void hist_kernel(const int* __restrict__ dst, int E, int* __restrict__ counts) {
    int i = blockIdx.x * blockDim.x + threadIdx.x;
    if (i < E) atomicAdd(&counts[dst[i]], 1);
}

__global__ __launch_bounds__(1024) void scan_kernel(const int* __restrict__ counts,
                                                    int* __restrict__ offsets, int N) {
    __shared__ int part[1024];
    const int t = threadIdx.x;
    const int chunk = (N + 1023) / 1024;
    const int b = t * chunk;
    const int e = min(b + chunk, N);
    int sum = 0;
    for (int i = b; i < e; ++i) sum += counts[i];
    part[t] = sum;
    __syncthreads();
    for (int off = 1; off < 1024; off <<= 1) {
        int v = (t >= off) ? part[t - off] : 0;
        __syncthreads();
        part[t] += v;
        __syncthreads();
    }
    int run = (t == 0) ? 0 : part[t - 1];
    for (int i = b; i < e; ++i) { offsets[i] = run; run += counts[i]; }
    if (t == 1023) offsets[N] = run;
}

__global__ void fill_kernel(const int* __restrict__ dst, const int* __restrict__ src, int E,
                            const int* __restrict__ offsets, int* __restrict__ cursor,
                            int* __restrict__ ssrc) {
    int i = blockIdx.x * blockDim.x + threadIdx.x;
    if (i < E) {
        int d = dst[i];
        int r = atomicAdd(&cursor[d], 1);
        ssrc[offsets[d] + r] = src[i];
    }
}

// ---------------- per-node online-softmax attention ----------------
// One wave per node. Lane l owns elements 4l..4l+3 (head = l>>3).
__global__ __launch_bounds__(256) void attn_kernel(
    const float* __restrict__ qbuf, const unsigned short* __restrict__ kb,
    const unsigned short* __restrict__ vb, const int* __restrict__ offsets,
    const int* __restrict__ ssrc, float* __restrict__ attn, int N)
{
    const int node = blockIdx.x * 4 + (threadIdx.x >> 6);
    if (node >= N) return;
    const int lane = threadIdx.x & 63;

    float4 q4 = *(const float4*)(qbuf + (size_t)node * D_MODEL + 4 * lane);
    const float sc = 0.17677669529663689f;  // 1/sqrt(32)
    q4.x *= sc; q4.y *= sc; q4.z *= sc; q4.w *= sc;

    float m = -INFINITY, l = 0.f;
    float ax = 0.f, ay = 0.f, az = 0.f, aw = 0.f;

    const int e0 = offsets[node], e1 = offsets[node + 1];
    for (int e = e0; e < e1; ++e) {
        const int s = ssrc[e];
        ushort4 ku = *(const ushort4*)(kb + (size_t)s * D_MODEL + 4 * lane);
        float p = q4.x * bf2f(ku.x) + q4.y * bf2f(ku.y) + q4.z * bf2f(ku.z) + q4.w * bf2f(ku.w);
        p += __shfl_xor(p, 1);
        p += __shfl_xor(p, 2);
        p += __shfl_xor(p, 4);   // all 8 lanes of the head now hold the score
        float mnew  = fmaxf(m, p);
        float alpha = __expf(m - mnew);   // 0 on first edge (m=-inf)
        float w     = __expf(p - mnew);
        ushort4 vu = *(const ushort4*)(vb + (size_t)s * D_MODEL + 4 * lane);
        ax = ax * alpha + w * bf2f(vu.x);
        ay = ay * alpha + w * bf2f(vu.y);
        az = az * alpha + w * bf2f(vu.z);
        aw = aw * alpha + w * bf2f(vu.w);
        l = l * alpha + w;
        m = mnew;
    }
    const float inv = (l > 0.f) ? 1.f / l : 0.f;  // deg-0 nodes -> 0 (ref: segment_sum of nothing)
    float4 o;
    o.x = ax * inv; o.y = ay * inv; o.z = az * inv; o.w = aw * inv;
    *(float4*)(attn + (size_t)node * D_MODEL + 4 * lane) = o;
}

// ---------------- launch ----------------
extern "C" void kernel_launch(void* const* d_in, const int* in_sizes, int n_in,
                              void* d_out, int out_size, void* d_ws, size_t ws_size,
                              hipStream_t stream)
{
    const float* query = (const float*)d_in[0];
    const float* key   = (const float*)d_in[1];
    const float* value = (const float*)d_in[2];
    const int*   edges = (const int*)d_in[3];
    const float* Wq = (const float*)d_in[4];
    const float* bq = (const float*)d_in[5];
    const float* Wk = (const float*)d_in[6];
    const float* bk = (const float*)d_in[7];
    const float* Wv = (const float*)d_in[8];
    const float* bv = (const float*)d_in[9];
    const float* Wo = (const float*)d_in[10];
    const float* bo = (const float*)d_in[11];
    float* out = (float*)d_out;

    const int N = in_sizes[0] / D_MODEL;
    const int E = in_sizes[3] / 2;
    const int* dst = edges;
    const int* src = edges + E;

    char* ws = (char*)d_ws;
    size_t off = 0;
    auto alloc = [&](size_t bytes) {
        void* p = ws + off;
        off += (bytes + 255) & ~(size_t)255;
        return p;
    };
    float*          qbuf  = (float*)alloc((size_t)N * D_MODEL * 4);
    unsigned short* kbuf  = (unsigned short*)alloc((size_t)N * D_MODEL * 2);
    unsigned short* vbuf  = (unsigned short*)alloc((size_t)N * D_MODEL * 2);
    float*          attn  = (float*)alloc((size_t)N * D_MODEL * 4);
    unsigned short* Wbuf  = (unsigned short*)alloc((size_t)4 * D_MODEL * D_MODEL * 2);
    int*            counts  = (int*)alloc((size_t)2 * N * 4);   // counts + cursor contiguous
    int*            cursor  = counts + N;
    int*            offsets = (int*)alloc((size_t)(N + 1) * 4);
    int*            ssrc    = (int*)alloc((size_t)E * 4);
    (void)cursor;

    hipMemsetAsync(counts, 0, (size_t)2 * N * 4, stream);

    conv_weights<<<(D_MODEL * D_MODEL + 255) / 256, 256, 0, stream>>>(Wq, Wk, Wv, Wo, Wbuf);

    const int mblocks = (N + 63) / 64;
    gemm_proj<0><<<mblocks, 256, 0, stream>>>(query, Wbuf,                      bq, qbuf, N);
    gemm_proj<1><<<mblocks, 256, 0, stream>>>(key,   Wbuf + D_MODEL * D_MODEL,  bk, kbuf, N);
    gemm_proj<1><<<mblocks, 256, 0, stream>>>(value, Wbuf + 2 * D_MODEL * D_MODEL, bv, vbuf, N);

    const int eblocks = (E + 255) / 256;
    hist_kernel<<<eblocks, 256, 0, stream>>>(dst, E, counts);
    scan_kernel<<<1, 1024, 0, stream>>>(counts, offsets, N);
    fill_kernel<<<eblocks, 256, 0, stream>>>(dst, src, E, offsets, counts + N, ssrc);
    attn_kernel<<<(N + 3) / 4, 256, 0, stream>>>(qbuf, kbuf, vbuf, offsets, ssrc, attn, N);

    gemm_proj<0><<<mblocks, 256, 0, stream>>>(attn, Wbuf + 3 * D_MODEL * D_MODEL, bo, out, N);
}

// Round 2
// 570.939 us; speedup vs baseline: 1.0476x; 1.0476x over previous
//
#include <hip/hip_runtime.h>
#include <hip/hip_bf16.h>
#include <cstdint>

#define D_MODEL 256
#define NHEADS 8
#define DK 32

typedef float f32x4 __attribute__((ext_vector_type(4)));
typedef __bf16 bf16x8 __attribute__((ext_vector_type(8)));

__device__ __forceinline__ unsigned short f2bf_rne(float f) {
    unsigned int u = __float_as_uint(f);
    u += 0x7FFF + ((u >> 16) & 1);
    return (unsigned short)(u >> 16);
}
__device__ __forceinline__ float bf2f(unsigned short h) {
    return __uint_as_float(((unsigned int)h) << 16);
}

// ---------------- weight fp32 -> bf16 conversion (all 4 weights) ----------------
__global__ void conv_weights(const float* __restrict__ Wq, const float* __restrict__ Wk,
                             const float* __restrict__ Wv, const float* __restrict__ Wo,
                             unsigned short* __restrict__ out) {
    int i = blockIdx.x * blockDim.x + threadIdx.x;
    if (i < D_MODEL * D_MODEL) {
        out[i]                         = f2bf_rne(Wq[i]);
        out[D_MODEL * D_MODEL + i]     = f2bf_rne(Wk[i]);
        out[2 * D_MODEL * D_MODEL + i] = f2bf_rne(Wv[i]);
        out[3 * D_MODEL * D_MODEL + i] = f2bf_rne(Wo[i]);
    }
}

// ---------------- GEMM: out[M,256] = A[M,256] @ W[256,256]^T + bias -------------
// BM=64 rows/block, BN=256 (full width; wave w covers cols 64w..64w+63).
// IN_BF16: A is bf16 (direct bf16x8 frag loads) else fp32 (in-register cvt).
// OUT_BF16: store bf16 else fp32. Output addressing: row*out_stride + out_off + col
// (lets K and V land interleaved in one 512-elem row).
// MFMA 16x16x32 bf16. A-frag: A[m=lane&15][k=quad*8+j]; B-frag: W[n=lane&15][k=quad*8+j];
// D: col=lane&15, row=quad*4+reg.
template <int IN_BF16, int OUT_BF16>
__global__ __launch_bounds__(256, 2) void gemm_proj(
    const void* __restrict__ Ap, const unsigned short* __restrict__ Wb,
    const float* __restrict__ bias, void* __restrict__ outp, int M,
    int out_stride, int out_off)
{
    const int lane  = threadIdx.x & 63;
    const int wave  = threadIdx.x >> 6;
    const int m0    = blockIdx.x * 64;
    const int nbase = wave * 64;
    const int mrow  = lane & 15;
    const int quad  = lane >> 4;

    f32x4 acc[4][4] = {};

    int arow[4];
#pragma unroll
    for (int mi = 0; mi < 4; ++mi) {
        int r = m0 + mi * 16 + mrow;
        arow[mi] = (r < M) ? r : (M - 1);   // clamp; stores are guarded
    }

#pragma unroll
    for (int kk = 0; kk < 8; ++kk) {
        const int kof = kk * 32 + quad * 8;
        bf16x8 afr[4];
#pragma unroll
        for (int mi = 0; mi < 4; ++mi) {
            if (IN_BF16) {
                const unsigned short* ap = (const unsigned short*)Ap + (size_t)arow[mi] * D_MODEL + kof;
                afr[mi] = *(const bf16x8*)ap;
            } else {
                const float* ap = (const float*)Ap + (size_t)arow[mi] * D_MODEL + kof;
                float4 x0 = *(const float4*)ap;
                float4 x1 = *(const float4*)(ap + 4);
                bf16x8 t;
                t[0] = (__bf16)x0.x; t[1] = (__bf16)x0.y; t[2] = (__bf16)x0.z; t[3] = (__bf16)x0.w;
                t[4] = (__bf16)x1.x; t[5] = (__bf16)x1.y; t[6] = (__bf16)x1.z; t[7] = (__bf16)x1.w;
                afr[mi] = t;
            }
        }
        bf16x8 bfr[4];
#pragma unroll
        for (int ni = 0; ni < 4; ++ni) {
            const unsigned short* bp = Wb + (size_t)(nbase + ni * 16 + mrow) * D_MODEL + kof;
            bfr[ni] = *(const bf16x8*)bp;
        }
#pragma unroll
        for (int mi = 0; mi < 4; ++mi)
#pragma unroll
            for (int ni = 0; ni < 4; ++ni)
                acc[mi][ni] = __builtin_amdgcn_mfma_f32_16x16x32_bf16(
                    afr[mi], bfr[ni], acc[mi][ni], 0, 0, 0);
    }

#pragma unroll
    for (int ni = 0; ni < 4; ++ni) {
        const int col = nbase + ni * 16 + mrow;
        const float bv = bias[col];
#pragma unroll
        for (int mi = 0; mi < 4; ++mi) {
#pragma unroll
            for (int r = 0; r < 4; ++r) {
                const int row = m0 + mi * 16 + quad * 4 + r;
                if (row < M) {
                    float val = acc[mi][ni][r] + bv;
                    size_t idx = (size_t)row * out_stride + out_off + col;
                    if (OUT_BF16)
                        ((unsigned short*)outp)[idx] = f2bf_rne(val);
                    else
                        ((float*)outp)[idx] = val;
                }
            }
        }
    }
}

// ---------------- CSR construction ----------------
__global__ void hist_kernel(const int* __restrict__ dst, int E, int* __restrict__ counts) {
    int i = blockIdx.x * blockDim.x + threadIdx.x;
    if (i < E) atomicAdd(&counts[dst[i]], 1);
}

__global__ __launch_bounds__(1024) void scan_kernel(const int* __restrict__ counts,
                                                    int* __restrict__ offsets, int N) {
    __shared__ int part[1024];
    const int t = threadIdx.x;
    const int chunk = (N + 1023) / 1024;
    const int b = t * chunk;
    const int e = min(b + chunk, N);
    int sum = 0;
    for (int i = b; i < e; ++i) sum += counts[i];
    part[t] = sum;
    __syncthreads();
    for (int off = 1; off < 1024; off <<= 1) {
        int v = (t >= off) ? part[t - off] : 0;
        __syncthreads();
        part[t] += v;
        __syncthreads();
    }
    int run = (t == 0) ? 0 : part[t - 1];
    for (int i = b; i < e; ++i) { offsets[i] = run; run += counts[i]; }
    if (t == 1023) offsets[N] = run;
}

__global__ void fill_kernel(const int* __restrict__ dst, const int* __restrict__ src, int E,
                            const int* __restrict__ offsets, int* __restrict__ cursor,
                            int* __restrict__ ssrc) {
    int i = blockIdx.x * blockDim.x + threadIdx.x;
    if (i < E) {
        int d = dst[i];
        int r = atomicAdd(&cursor[d], 1);
        ssrc[offsets[d] + r] = src[i];
    }
}

// ---------------- per-node online-softmax attention ----------------
// One wave per node. Lane l owns elements 4l..4l+3 (head = l>>3).
// kv layout: row s = [K(256 bf16) | V(256 bf16)], 1 KB per node.
// 4-edge unroll for memory-level parallelism.
__global__ __launch_bounds__(256) void attn_kernel(
    const unsigned short* __restrict__ qb, const unsigned short* __restrict__ kv,
    const int* __restrict__ offsets, const int* __restrict__ ssrc,
    unsigned short* __restrict__ attn, int N)
{
    const int node = blockIdx.x * 4 + (threadIdx.x >> 6);
    if (node >= N) return;
    const int lane = threadIdx.x & 63;

    ushort4 qu = *(const ushort4*)(qb + (size_t)node * D_MODEL + 4 * lane);
    const float sc = 0.17677669529663689f;  // 1/sqrt(32)
    float qx = bf2f(qu.x) * sc, qy = bf2f(qu.y) * sc,
          qz = bf2f(qu.z) * sc, qw = bf2f(qu.w) * sc;

    float m = -INFINITY, l = 0.f;
    float ax = 0.f, ay = 0.f, az = 0.f, aw = 0.f;

    const int e0 = offsets[node], e1 = offsets[node + 1];
    int e = e0;

    for (; e + 3 < e1; e += 4) {
        int s0 = ssrc[e], s1 = ssrc[e + 1], s2 = ssrc[e + 2], s3 = ssrc[e + 3];
        const unsigned short* b0 = kv + (size_t)s0 * 512;
        const unsigned short* b1 = kv + (size_t)s1 * 512;
        const unsigned short* b2 = kv + (size_t)s2 * 512;
        const unsigned short* b3 = kv + (size_t)s3 * 512;
        ushort4 k0 = *(const ushort4*)(b0 + 4 * lane);
        ushort4 k1 = *(const ushort4*)(b1 + 4 * lane);
        ushort4 k2 = *(const ushort4*)(b2 + 4 * lane);
        ushort4 k3 = *(const ushort4*)(b3 + 4 * lane);
        ushort4 v0 = *(const ushort4*)(b0 + D_MODEL + 4 * lane);
        ushort4 v1 = *(const ushort4*)(b1 + D_MODEL + 4 * lane);
        ushort4 v2 = *(const ushort4*)(b2 + D_MODEL + 4 * lane);
        ushort4 v3 = *(const ushort4*)(b3 + D_MODEL + 4 * lane);

        float p0 = qx * bf2f(k0.x) + qy * bf2f(k0.y) + qz * bf2f(k0.z) + qw * bf2f(k0.w);
        float p1 = qx * bf2f(k1.x) + qy * bf2f(k1.y) + qz * bf2f(k1.z) + qw * bf2f(k1.w);
        float p2 = qx * bf2f(k2.x) + qy * bf2f(k2.y) + qz * bf2f(k2.z) + qw * bf2f(k2.w);
        float p3 = qx * bf2f(k3.x) + qy * bf2f(k3.y) + qz * bf2f(k3.z) + qw * bf2f(k3.w);
#pragma unroll
        for (int d = 1; d <= 4; d <<= 1) {
            p0 += __shfl_xor(p0, d);
            p1 += __shfl_xor(p1, d);
            p2 += __shfl_xor(p2, d);
            p3 += __shfl_xor(p3, d);
        }
        float mnew = fmaxf(fmaxf(fmaxf(m, p0), fmaxf(p1, p2)), p3);
        float alpha = __expf(m - mnew);     // 0 on first group (m=-inf)
        float w0 = __expf(p0 - mnew), w1 = __expf(p1 - mnew);
        float w2 = __expf(p2 - mnew), w3 = __expf(p3 - mnew);
        ax = ax * alpha + w0 * bf2f(v0.x) + w1 * bf2f(v1.x) + w2 * bf2f(v2.x) + w3 * bf2f(v3.x);
        ay = ay * alpha + w0 * bf2f(v0.y) + w1 * bf2f(v1.y) + w2 * bf2f(v2.y) + w3 * bf2f(v3.y);
        az = az * alpha + w0 * bf2f(v0.z) + w1 * bf2f(v1.z) + w2 * bf2f(v2.z) + w3 * bf2f(v3.z);
        aw = aw * alpha + w0 * bf2f(v0.w) + w1 * bf2f(v1.w) + w2 * bf2f(v2.w) + w3 * bf2f(v3.w);
        l = l * alpha + w0 + w1 + w2 + w3;
        m = mnew;
    }
    for (; e < e1; ++e) {
        int s = ssrc[e];
        const unsigned short* b = kv + (size_t)s * 512;
        ushort4 ku = *(const ushort4*)(b + 4 * lane);
        ushort4 vu = *(const ushort4*)(b + D_MODEL + 4 * lane);
        float p = qx * bf2f(ku.x) + qy * bf2f(ku.y) + qz * bf2f(ku.z) + qw * bf2f(ku.w);
        p += __shfl_xor(p, 1);
        p += __shfl_xor(p, 2);
        p += __shfl_xor(p, 4);
        float mnew  = fmaxf(m, p);
        float alpha = __expf(m - mnew);
        float w     = __expf(p - mnew);
        ax = ax * alpha + w * bf2f(vu.x);
        ay = ay * alpha + w * bf2f(vu.y);
        az = az * alpha + w * bf2f(vu.z);
        aw = aw * alpha + w * bf2f(vu.w);
        l = l * alpha + w;
        m = mnew;
    }

    const float inv = (l > 0.f) ? 1.f / l : 0.f;  // deg-0 nodes -> zeros
    ushort4 o;
    o.x = f2bf_rne(ax * inv);
    o.y = f2bf_rne(ay * inv);
    o.z = f2bf_rne(az * inv);
    o.w = f2bf_rne(aw * inv);
    *(ushort4*)(attn + (size_t)node * D_MODEL + 4 * lane) = o;
}

// ---------------- launch ----------------
extern "C" void kernel_launch(void* const* d_in, const int* in_sizes, int n_in,
                              void* d_out, int out_size, void* d_ws, size_t ws_size,
                              hipStream_t stream)
{
    const float* query = (const float*)d_in[0];
    const float* key   = (const float*)d_in[1];
    const float* value = (const float*)d_in[2];
    const int*   edges = (const int*)d_in[3];
    const float* Wq = (const float*)d_in[4];
    const float* bq = (const float*)d_in[5];
    const float* Wk = (const float*)d_in[6];
    const float* bk = (const float*)d_in[7];
    const float* Wv = (const float*)d_in[8];
    const float* bv = (const float*)d_in[9];
    const float* Wo = (const float*)d_in[10];
    const float* bo = (const float*)d_in[11];
    float* out = (float*)d_out;

    const int N = in_sizes[0] / D_MODEL;
    const int E = in_sizes[3] / 2;
    const int* dst = edges;
    const int* src = edges + E;

    char* ws = (char*)d_ws;
    size_t off = 0;
    auto alloc = [&](size_t bytes) {
        void* p = ws + off;
        off += (bytes + 255) & ~(size_t)255;
        return p;
    };
    unsigned short* qbuf  = (unsigned short*)alloc((size_t)N * D_MODEL * 2);
    unsigned short* kvbuf = (unsigned short*)alloc((size_t)N * 2 * D_MODEL * 2); // K|V interleaved
    unsigned short* attnb = (unsigned short*)alloc((size_t)N * D_MODEL * 2);
    unsigned short* Wbuf  = (unsigned short*)alloc((size_t)4 * D_MODEL * D_MODEL * 2);
    int*            counts  = (int*)alloc((size_t)2 * N * 4);   // counts + cursor contiguous
    int*            offsets = (int*)alloc((size_t)(N + 1) * 4);
    int*            ssrc    = (int*)alloc((size_t)E * 4);

    hipMemsetAsync(counts, 0, (size_t)2 * N * 4, stream);

    conv_weights<<<(D_MODEL * D_MODEL + 255) / 256, 256, 0, stream>>>(Wq, Wk, Wv, Wo, Wbuf);

    const int mblocks = (N + 63) / 64;
    gemm_proj<0, 1><<<mblocks, 256, 0, stream>>>(query, Wbuf,                        bq, qbuf,  N, D_MODEL, 0);
    gemm_proj<0, 1><<<mblocks, 256, 0, stream>>>(key,   Wbuf + D_MODEL * D_MODEL,    bk, kvbuf, N, 2 * D_MODEL, 0);
    gemm_proj<0, 1><<<mblocks, 256, 0, stream>>>(value, Wbuf + 2 * D_MODEL * D_MODEL, bv, kvbuf, N, 2 * D_MODEL, D_MODEL);

    const int eblocks = (E + 255) / 256;
    hist_kernel<<<eblocks, 256, 0, stream>>>(dst, E, counts);
    scan_kernel<<<1, 1024, 0, stream>>>(counts, offsets, N);
    fill_kernel<<<eblocks, 256, 0, stream>>>(dst, src, E, offsets, counts + N, ssrc);
    attn_kernel<<<(N + 3) / 4, 256, 0, stream>>>(qbuf, kvbuf, offsets, ssrc, attnb, N);

    gemm_proj<1, 0><<<mblocks, 256, 0, stream>>>(attnb, Wbuf + 3 * D_MODEL * D_MODEL, bo, out, N, D_MODEL, 0);
}

// Round 3
// 505.116 us; speedup vs baseline: 1.1842x; 1.1303x over previous
//
#include <hip/hip_runtime.h>
#include <hip/hip_bf16.h>
#include <cstdint>

#define D_MODEL 256
#define NHEADS 8
#define DK 32

typedef float f32x4 __attribute__((ext_vector_type(4)));
typedef __bf16 bf16x8 __attribute__((ext_vector_type(8)));

__device__ __forceinline__ unsigned short f2bf_rne(float f) {
    unsigned int u = __float_as_uint(f);
    u += 0x7FFF + ((u >> 16) & 1);
    return (unsigned short)(u >> 16);
}
__device__ __forceinline__ float bf2f(unsigned short h) {
    return __uint_as_float(((unsigned int)h) << 16);
}

// ---------------- weight fp32 -> bf16 conversion (all 4 weights) ----------------
__global__ void conv_weights(const float* __restrict__ Wq, const float* __restrict__ Wk,
                             const float* __restrict__ Wv, const float* __restrict__ Wo,
                             unsigned short* __restrict__ out) {
    int i = blockIdx.x * blockDim.x + threadIdx.x;
    if (i < D_MODEL * D_MODEL) {
        out[i]                         = f2bf_rne(Wq[i]);
        out[D_MODEL * D_MODEL + i]     = f2bf_rne(Wk[i]);
        out[2 * D_MODEL * D_MODEL + i] = f2bf_rne(Wv[i]);
        out[3 * D_MODEL * D_MODEL + i] = f2bf_rne(Wo[i]);
    }
}

// ---------------- GEMM: out[M,256] = A[M,256] @ W[256,256]^T + bias -------------
// BM=64 rows/block, BN=256 (full width; wave w covers cols 64w..64w+63).
// IN_BF16: A is bf16 (direct bf16x8 frag loads) else fp32 (in-register cvt).
// OUT_BF16: store bf16 else fp32. Output addressing: row*out_stride + out_off + col.
// MFMA 16x16x32 bf16. A-frag: A[m=lane&15][k=quad*8+j]; B-frag: W[n=lane&15][k=quad*8+j];
// D: col=lane&15, row=quad*4+reg.
template <int IN_BF16, int OUT_BF16>
__global__ __launch_bounds__(256, 2) void gemm_proj(
    const void* __restrict__ Ap, const unsigned short* __restrict__ Wb,
    const float* __restrict__ bias, void* __restrict__ outp, int M,
    int out_stride, int out_off)
{
    const int lane  = threadIdx.x & 63;
    const int wave  = threadIdx.x >> 6;
    const int m0    = blockIdx.x * 64;
    const int nbase = wave * 64;
    const int mrow  = lane & 15;
    const int quad  = lane >> 4;

    f32x4 acc[4][4] = {};

    int arow[4];
#pragma unroll
    for (int mi = 0; mi < 4; ++mi) {
        int r = m0 + mi * 16 + mrow;
        arow[mi] = (r < M) ? r : (M - 1);   // clamp; stores are guarded
    }

#pragma unroll
    for (int kk = 0; kk < 8; ++kk) {
        const int kof = kk * 32 + quad * 8;
        bf16x8 afr[4];
#pragma unroll
        for (int mi = 0; mi < 4; ++mi) {
            if (IN_BF16) {
                const unsigned short* ap = (const unsigned short*)Ap + (size_t)arow[mi] * D_MODEL + kof;
                afr[mi] = *(const bf16x8*)ap;
            } else {
                const float* ap = (const float*)Ap + (size_t)arow[mi] * D_MODEL + kof;
                float4 x0 = *(const float4*)ap;
                float4 x1 = *(const float4*)(ap + 4);
                bf16x8 t;
                t[0] = (__bf16)x0.x; t[1] = (__bf16)x0.y; t[2] = (__bf16)x0.z; t[3] = (__bf16)x0.w;
                t[4] = (__bf16)x1.x; t[5] = (__bf16)x1.y; t[6] = (__bf16)x1.z; t[7] = (__bf16)x1.w;
                afr[mi] = t;
            }
        }
        bf16x8 bfr[4];
#pragma unroll
        for (int ni = 0; ni < 4; ++ni) {
            const unsigned short* bp = Wb + (size_t)(nbase + ni * 16 + mrow) * D_MODEL + kof;
            bfr[ni] = *(const bf16x8*)bp;
        }
#pragma unroll
        for (int mi = 0; mi < 4; ++mi)
#pragma unroll
            for (int ni = 0; ni < 4; ++ni)
                acc[mi][ni] = __builtin_amdgcn_mfma_f32_16x16x32_bf16(
                    afr[mi], bfr[ni], acc[mi][ni], 0, 0, 0);
    }

#pragma unroll
    for (int ni = 0; ni < 4; ++ni) {
        const int col = nbase + ni * 16 + mrow;
        const float bv = bias[col];
#pragma unroll
        for (int mi = 0; mi < 4; ++mi) {
#pragma unroll
            for (int r = 0; r < 4; ++r) {
                const int row = m0 + mi * 16 + quad * 4 + r;
                if (row < M) {
                    float val = acc[mi][ni][r] + bv;
                    size_t idx = (size_t)row * out_stride + out_off + col;
                    if (OUT_BF16)
                        ((unsigned short*)outp)[idx] = f2bf_rne(val);
                    else
                        ((float*)outp)[idx] = val;
                }
            }
        }
    }
}

// ---------------- CSR construction ----------------
__global__ void hist_kernel(const int* __restrict__ dst, int E, int* __restrict__ counts) {
    int i = blockIdx.x * blockDim.x + threadIdx.x;
    if (i < E) atomicAdd(&counts[dst[i]], 1);
}

// Hierarchical exclusive scan over counts[0..N-1] (zero-padded), writing
// offsets[0..N]. Grid G = ceil((N+1)/256) blocks; requires G <= 256.
__global__ void block_reduce_kernel(const int* __restrict__ counts, int N,
                                    int* __restrict__ blockSums) {
    const int g = blockIdx.x * 256 + threadIdx.x;
    int v = (g < N) ? counts[g] : 0;
#pragma unroll
    for (int d = 1; d < 64; d <<= 1) v += __shfl_xor(v, d);
    __shared__ int ws[4];
    if ((threadIdx.x & 63) == 0) ws[threadIdx.x >> 6] = v;
    __syncthreads();
    if (threadIdx.x == 0) blockSums[blockIdx.x] = ws[0] + ws[1] + ws[2] + ws[3];
}

__global__ void scan_blocks_kernel(int* __restrict__ blockSums, int G) {
    __shared__ int sh[256];
    const int t = threadIdx.x;
    int v = (t < G) ? blockSums[t] : 0;
    sh[t] = v;
    __syncthreads();
#pragma unroll
    for (int off = 1; off < 256; off <<= 1) {
        int add = (t >= off) ? sh[t - off] : 0;
        __syncthreads();
        sh[t] += add;
        __syncthreads();
    }
    if (t < G) blockSums[t] = sh[t] - v;   // exclusive
}

__global__ void scan_write_kernel(const int* __restrict__ counts, int N,
                                  const int* __restrict__ blockOffsets,
                                  int* __restrict__ offsets) {
    const int g = blockIdx.x * 256 + threadIdx.x;
    const int t = threadIdx.x;
    int v = (g < N) ? counts[g] : 0;
    __shared__ int sh[256];
    sh[t] = v;
    __syncthreads();
#pragma unroll
    for (int off = 1; off < 256; off <<= 1) {
        int add = (t >= off) ? sh[t - off] : 0;
        __syncthreads();
        sh[t] += add;
        __syncthreads();
    }
    if (g <= N) offsets[g] = sh[t] - v + blockOffsets[blockIdx.x];
}

__global__ void fill_kernel(const int* __restrict__ dst, const int* __restrict__ src, int E,
                            const int* __restrict__ offsets, int* __restrict__ cursor,
                            int* __restrict__ ssrc) {
    int i = blockIdx.x * blockDim.x + threadIdx.x;
    if (i < E) {
        int d = dst[i];
        int r = atomicAdd(&cursor[d], 1);
        ssrc[offsets[d] + r] = src[i];
    }
}

// ---------------- per-node online-softmax attention ----------------
// One wave per node. Lane l owns elements 4l..4l+3 (head = l>>3).
// kv layout: row s = [K(256 bf16) | V(256 bf16)], 1 KB per node.
// 4-edge unroll for memory-level parallelism.
__global__ __launch_bounds__(256) void attn_kernel(
    const unsigned short* __restrict__ qb, const unsigned short* __restrict__ kv,
    const int* __restrict__ offsets, const int* __restrict__ ssrc,
    unsigned short* __restrict__ attn, int N)
{
    const int node = blockIdx.x * 4 + (threadIdx.x >> 6);
    if (node >= N) return;
    const int lane = threadIdx.x & 63;

    ushort4 qu = *(const ushort4*)(qb + (size_t)node * D_MODEL + 4 * lane);
    const float sc = 0.17677669529663689f;  // 1/sqrt(32)
    float qx = bf2f(qu.x) * sc, qy = bf2f(qu.y) * sc,
          qz = bf2f(qu.z) * sc, qw = bf2f(qu.w) * sc;

    float m = -INFINITY, l = 0.f;
    float ax = 0.f, ay = 0.f, az = 0.f, aw = 0.f;

    const int e0 = offsets[node], e1 = offsets[node + 1];
    int e = e0;

    for (; e + 3 < e1; e += 4) {
        int s0 = ssrc[e], s1 = ssrc[e + 1], s2 = ssrc[e + 2], s3 = ssrc[e + 3];
        const unsigned short* b0 = kv + (size_t)s0 * 512;
        const unsigned short* b1 = kv + (size_t)s1 * 512;
        const unsigned short* b2 = kv + (size_t)s2 * 512;
        const unsigned short* b3 = kv + (size_t)s3 * 512;
        ushort4 k0 = *(const ushort4*)(b0 + 4 * lane);
        ushort4 k1 = *(const ushort4*)(b1 + 4 * lane);
        ushort4 k2 = *(const ushort4*)(b2 + 4 * lane);
        ushort4 k3 = *(const ushort4*)(b3 + 4 * lane);
        ushort4 v0 = *(const ushort4*)(b0 + D_MODEL + 4 * lane);
        ushort4 v1 = *(const ushort4*)(b1 + D_MODEL + 4 * lane);
        ushort4 v2 = *(const ushort4*)(b2 + D_MODEL + 4 * lane);
        ushort4 v3 = *(const ushort4*)(b3 + D_MODEL + 4 * lane);

        float p0 = qx * bf2f(k0.x) + qy * bf2f(k0.y) + qz * bf2f(k0.z) + qw * bf2f(k0.w);
        float p1 = qx * bf2f(k1.x) + qy * bf2f(k1.y) + qz * bf2f(k1.z) + qw * bf2f(k1.w);
        float p2 = qx * bf2f(k2.x) + qy * bf2f(k2.y) + qz * bf2f(k2.z) + qw * bf2f(k2.w);
        float p3 = qx * bf2f(k3.x) + qy * bf2f(k3.y) + qz * bf2f(k3.z) + qw * bf2f(k3.w);
#pragma unroll
        for (int d = 1; d <= 4; d <<= 1) {
            p0 += __shfl_xor(p0, d);
            p1 += __shfl_xor(p1, d);
            p2 += __shfl_xor(p2, d);
            p3 += __shfl_xor(p3, d);
        }
        float mnew = fmaxf(fmaxf(fmaxf(m, p0), fmaxf(p1, p2)), p3);
        float alpha = __expf(m - mnew);     // 0 on first group (m=-inf)
        float w0 = __expf(p0 - mnew), w1 = __expf(p1 - mnew);
        float w2 = __expf(p2 - mnew), w3 = __expf(p3 - mnew);
        ax = ax * alpha + w0 * bf2f(v0.x) + w1 * bf2f(v1.x) + w2 * bf2f(v2.x) + w3 * bf2f(v3.x);
        ay = ay * alpha + w0 * bf2f(v0.y) + w1 * bf2f(v1.y) + w2 * bf2f(v2.y) + w3 * bf2f(v3.y);
        az = az * alpha + w0 * bf2f(v0.z) + w1 * bf2f(v1.z) + w2 * bf2f(v2.z) + w3 * bf2f(v3.z);
        aw = aw * alpha + w0 * bf2f(v0.w) + w1 * bf2f(v1.w) + w2 * bf2f(v2.w) + w3 * bf2f(v3.w);
        l = l * alpha + w0 + w1 + w2 + w3;
        m = mnew;
    }
    for (; e < e1; ++e) {
        int s = ssrc[e];
        const unsigned short* b = kv + (size_t)s * 512;
        ushort4 ku = *(const ushort4*)(b + 4 * lane);
        ushort4 vu = *(const ushort4*)(b + D_MODEL + 4 * lane);
        float p = qx * bf2f(ku.x) + qy * bf2f(ku.y) + qz * bf2f(ku.z) + qw * bf2f(ku.w);
        p += __shfl_xor(p, 1);
        p += __shfl_xor(p, 2);
        p += __shfl_xor(p, 4);
        float mnew  = fmaxf(m, p);
        float alpha = __expf(m - mnew);
        float w     = __expf(p - mnew);
        ax = ax * alpha + w * bf2f(vu.x);
        ay = ay * alpha + w * bf2f(vu.y);
        az = az * alpha + w * bf2f(vu.z);
        aw = aw * alpha + w * bf2f(vu.w);
        l = l * alpha + w;
        m = mnew;
    }

    const float inv = (l > 0.f) ? 1.f / l : 0.f;  // deg-0 nodes -> zeros
    ushort4 o;
    o.x = f2bf_rne(ax * inv);
    o.y = f2bf_rne(ay * inv);
    o.z = f2bf_rne(az * inv);
    o.w = f2bf_rne(aw * inv);
    *(ushort4*)(attn + (size_t)node * D_MODEL + 4 * lane) = o;
}

// ---------------- launch ----------------
extern "C" void kernel_launch(void* const* d_in, const int* in_sizes, int n_in,
                              void* d_out, int out_size, void* d_ws, size_t ws_size,
                              hipStream_t stream)
{
    const float* query = (const float*)d_in[0];
    const float* key   = (const float*)d_in[1];
    const float* value = (const float*)d_in[2];
    const int*   edges = (const int*)d_in[3];
    const float* Wq = (const float*)d_in[4];
    const float* bq = (const float*)d_in[5];
    const float* Wk = (const float*)d_in[6];
    const float* bk = (const float*)d_in[7];
    const float* Wv = (const float*)d_in[8];
    const float* bv = (const float*)d_in[9];
    const float* Wo = (const float*)d_in[10];
    const float* bo = (const float*)d_in[11];
    float* out = (float*)d_out;

    const int N = in_sizes[0] / D_MODEL;
    const int E = in_sizes[3] / 2;
    const int* dst = edges;
    const int* src = edges + E;

    char* ws = (char*)d_ws;
    size_t off = 0;
    auto alloc = [&](size_t bytes) {
        void* p = ws + off;
        off += (bytes + 255) & ~(size_t)255;
        return p;
    };
    unsigned short* qbuf  = (unsigned short*)alloc((size_t)N * D_MODEL * 2);
    unsigned short* kvbuf = (unsigned short*)alloc((size_t)N * 2 * D_MODEL * 2); // K|V interleaved
    unsigned short* attnb = (unsigned short*)alloc((size_t)N * D_MODEL * 2);
    unsigned short* Wbuf  = (unsigned short*)alloc((size_t)4 * D_MODEL * D_MODEL * 2);
    int*            counts  = (int*)alloc((size_t)2 * N * 4);   // counts + cursor contiguous
    int*            offsets = (int*)alloc((size_t)(N + 1) * 4);
    int*            ssrc    = (int*)alloc((size_t)E * 4);
    int*            bsums   = (int*)alloc((size_t)256 * 4);

    hipMemsetAsync(counts, 0, (size_t)2 * N * 4, stream);

    conv_weights<<<(D_MODEL * D_MODEL + 255) / 256, 256, 0, stream>>>(Wq, Wk, Wv, Wo, Wbuf);

    const int mblocks = (N + 63) / 64;
    gemm_proj<0, 1><<<mblocks, 256, 0, stream>>>(query, Wbuf,                        bq, qbuf,  N, D_MODEL, 0);
    gemm_proj<0, 1><<<mblocks, 256, 0, stream>>>(key,   Wbuf + D_MODEL * D_MODEL,    bk, kvbuf, N, 2 * D_MODEL, 0);
    gemm_proj<0, 1><<<mblocks, 256, 0, stream>>>(value, Wbuf + 2 * D_MODEL * D_MODEL, bv, kvbuf, N, 2 * D_MODEL, D_MODEL);

    const int eblocks = (E + 255) / 256;
    hist_kernel<<<eblocks, 256, 0, stream>>>(dst, E, counts);

    const int G = (N + 256) / 256;  // ceil((N+1)/256), covers g == N
    block_reduce_kernel<<<G, 256, 0, stream>>>(counts, N, bsums);
    scan_blocks_kernel<<<1, 256, 0, stream>>>(bsums, G);
    scan_write_kernel<<<G, 256, 0, stream>>>(counts, N, bsums, offsets);

    fill_kernel<<<eblocks, 256, 0, stream>>>(dst, src, E, offsets, counts + N, ssrc);
    attn_kernel<<<(N + 3) / 4, 256, 0, stream>>>(qbuf, kvbuf, offsets, ssrc, attnb, N);

    gemm_proj<1, 0><<<mblocks, 256, 0, stream>>>(attnb, Wbuf + 3 * D_MODEL * D_MODEL, bo, out, N, D_MODEL, 0);
}

// Round 4
// 464.711 us; speedup vs baseline: 1.2871x; 1.0869x over previous
//
#include <hip/hip_runtime.h>
#include <hip/hip_bf16.h>
#include <cstdint>

#define D_MODEL 256
#define NHEADS 8
#define DK 32
#define LDSPAD 8
#define LDSROW (D_MODEL + LDSPAD)   // 264 bf16 per LDS row

typedef float f32x4 __attribute__((ext_vector_type(4)));
typedef __bf16 bf16x8 __attribute__((ext_vector_type(8)));

__device__ __forceinline__ unsigned short f2bf_rne(float f) {
    unsigned int u = __float_as_uint(f);
    u += 0x7FFF + ((u >> 16) & 1);
    return (unsigned short)(u >> 16);
}
__device__ __forceinline__ float bf2f(unsigned short h) {
    return __uint_as_float(((unsigned int)h) << 16);
}

// ---------------- weight fp32 -> bf16, pre-swizzled into MFMA B-fragment order ---
// Layout: for weight w, fragment block (ntile 0..15, kk 0..7): 1 KB containing
// lane-major bf16x8: elem j of lane l = W[ntile*16 + (l&15)][kk*32 + (l>>4)*8 + j].
// GEMM B-load becomes one contiguous 16 B/lane read (perfect coalescing).
__global__ void conv_weights(const float* __restrict__ W0, const float* __restrict__ W1,
                             const float* __restrict__ W2, const float* __restrict__ W3,
                             unsigned short* __restrict__ out) {
    int i = blockIdx.x * blockDim.x + threadIdx.x;   // 4 * 16*8*64 = 32768 threads
    if (i >= 4 * 8192) return;
    const int w    = i >> 13;
    const int rem  = i & 8191;            // (ntile*8 + kk)*64 + lane
    const int lane = rem & 63;
    const int kk   = (rem >> 6) & 7;
    const int ntile= rem >> 9;
    const int row  = ntile * 16 + (lane & 15);
    const int col  = kk * 32 + (lane >> 4) * 8;
    const float* Wsrc = (w == 0) ? W0 : (w == 1) ? W1 : (w == 2) ? W2 : W3;
    const float* sp = Wsrc + (size_t)row * D_MODEL + col;
    float4 x0 = *(const float4*)sp;
    float4 x1 = *(const float4*)(sp + 4);
    unsigned short* dp = out + (size_t)w * D_MODEL * D_MODEL + (size_t)rem * 8;
    ushort4 o0, o1;
    o0.x = f2bf_rne(x0.x); o0.y = f2bf_rne(x0.y); o0.z = f2bf_rne(x0.z); o0.w = f2bf_rne(x0.w);
    o1.x = f2bf_rne(x1.x); o1.y = f2bf_rne(x1.y); o1.z = f2bf_rne(x1.z); o1.w = f2bf_rne(x1.w);
    *(ushort4*)dp = o0;
    *(ushort4*)(dp + 4) = o1;
}

// ---------------- GEMM: out[M,256] = A[M,256] @ W[256,256]^T + bias -------------
// BM=64 rows/block, BN=256 (wave w covers cols 64w..64w+63). K=256 in one pass.
// A staged through LDS (coalesced global loads + fp32->bf16 cvt), fragments via
// ds_read_b128 (row stride 264 -> all 32 banks busy). B from pre-swizzled global
// (1 KB contiguous per fragment load, L1/L2-resident).
// MFMA 16x16x32 bf16. A-frag: A[m=lane&15][k=quad*8+j]; B-frag: W[n=lane&15][k=quad*8+j];
// D: col=lane&15, row=quad*4+reg.
template <int IN_BF16, int OUT_BF16>
__global__ __launch_bounds__(256, 3) void gemm_proj(
    const void* __restrict__ Ap, const unsigned short* __restrict__ Wsw,
    const float* __restrict__ bias, void* __restrict__ outp, int M,
    int out_stride, int out_off)
{
    __shared__ __align__(16) unsigned short smem[64 * LDSROW];

    const int lane  = threadIdx.x & 63;
    const int wave  = threadIdx.x >> 6;
    const int m0    = blockIdx.x * 64;
    const int mrow  = lane & 15;
    const int quad  = lane >> 4;

    // ---- stage A tile (64 x 256) into LDS as bf16 ----
    if (IN_BF16) {
        const unsigned short* Ab = (const unsigned short*)Ap;
#pragma unroll
        for (int i = 0; i < 8; ++i) {
            const int g = i * 256 + threadIdx.x;     // ushort8 index
            const int r = g >> 5, c8 = g & 31;
            const int grow = min(m0 + r, M - 1);
            bf16x8 x = *(const bf16x8*)(Ab + (size_t)grow * D_MODEL + c8 * 8);
            *(bf16x8*)(smem + r * LDSROW + c8 * 8) = x;
        }
    } else {
        const float* Af = (const float*)Ap;
#pragma unroll
        for (int i = 0; i < 16; ++i) {
            const int g = i * 256 + threadIdx.x;     // float4 index
            const int r = g >> 6, c4 = g & 63;
            const int grow = min(m0 + r, M - 1);
            float4 x = *(const float4*)(Af + (size_t)grow * D_MODEL + c4 * 4);
            ushort4 o;
            o.x = f2bf_rne(x.x); o.y = f2bf_rne(x.y);
            o.z = f2bf_rne(x.z); o.w = f2bf_rne(x.w);
            *(ushort4*)(smem + r * LDSROW + c4 * 4) = o;
        }
    }
    __syncthreads();

    f32x4 acc[4][4] = {};

#pragma unroll
    for (int kk = 0; kk < 8; ++kk) {
        bf16x8 afr[4];
#pragma unroll
        for (int mi = 0; mi < 4; ++mi)
            afr[mi] = *(const bf16x8*)(smem + (mi * 16 + mrow) * LDSROW + kk * 32 + quad * 8);
        bf16x8 bfr[4];
#pragma unroll
        for (int ni = 0; ni < 4; ++ni) {
            const int ntile = wave * 4 + ni;
            bfr[ni] = *(const bf16x8*)(Wsw + ((size_t)(ntile * 8 + kk) * 64 + lane) * 8);
        }
#pragma unroll
        for (int mi = 0; mi < 4; ++mi)
#pragma unroll
            for (int ni = 0; ni < 4; ++ni)
                acc[mi][ni] = __builtin_amdgcn_mfma_f32_16x16x32_bf16(
                    afr[mi], bfr[ni], acc[mi][ni], 0, 0, 0);
    }

#pragma unroll
    for (int ni = 0; ni < 4; ++ni) {
        const int col = wave * 64 + ni * 16 + mrow;
        const float bv = bias[col];
#pragma unroll
        for (int mi = 0; mi < 4; ++mi) {
#pragma unroll
            for (int r = 0; r < 4; ++r) {
                const int row = m0 + mi * 16 + quad * 4 + r;
                if (row < M) {
                    float val = acc[mi][ni][r] + bv;
                    size_t idx = (size_t)row * out_stride + out_off + col;
                    if (OUT_BF16)
                        ((unsigned short*)outp)[idx] = f2bf_rne(val);
                    else
                        ((float*)outp)[idx] = val;
                }
            }
        }
    }
}

// ---------------- CSR construction ----------------
__global__ void hist_kernel(const int* __restrict__ dst, int E, int* __restrict__ counts) {
    int i = blockIdx.x * blockDim.x + threadIdx.x;
    if (i < E) atomicAdd(&counts[dst[i]], 1);
}

// Hierarchical exclusive scan over counts[0..N-1], writing offsets[0..N].
__global__ void block_reduce_kernel(const int* __restrict__ counts, int N,
                                    int* __restrict__ blockSums) {
    const int g = blockIdx.x * 256 + threadIdx.x;
    int v = (g < N) ? counts[g] : 0;
#pragma unroll
    for (int d = 1; d < 64; d <<= 1) v += __shfl_xor(v, d);
    __shared__ int ws[4];
    if ((threadIdx.x & 63) == 0) ws[threadIdx.x >> 6] = v;
    __syncthreads();
    if (threadIdx.x == 0) blockSums[blockIdx.x] = ws[0] + ws[1] + ws[2] + ws[3];
}

__global__ void scan_blocks_kernel(int* __restrict__ blockSums, int G) {
    __shared__ int sh[256];
    const int t = threadIdx.x;
    int v = (t < G) ? blockSums[t] : 0;
    sh[t] = v;
    __syncthreads();
#pragma unroll
    for (int off = 1; off < 256; off <<= 1) {
        int add = (t >= off) ? sh[t - off] : 0;
        __syncthreads();
        sh[t] += add;
        __syncthreads();
    }
    if (t < G) blockSums[t] = sh[t] - v;   // exclusive
}

__global__ void scan_write_kernel(const int* __restrict__ counts, int N,
                                  const int* __restrict__ blockOffsets,
                                  int* __restrict__ offsets) {
    const int g = blockIdx.x * 256 + threadIdx.x;
    const int t = threadIdx.x;
    int v = (g < N) ? counts[g] : 0;
    __shared__ int sh[256];
    sh[t] = v;
    __syncthreads();
#pragma unroll
    for (int off = 1; off < 256; off <<= 1) {
        int add = (t >= off) ? sh[t - off] : 0;
        __syncthreads();
        sh[t] += add;
        __syncthreads();
    }
    if (g <= N) offsets[g] = sh[t] - v + blockOffsets[blockIdx.x];
}

__global__ void fill_kernel(const int* __restrict__ dst, const int* __restrict__ src, int E,
                            const int* __restrict__ offsets, int* __restrict__ cursor,
                            int* __restrict__ ssrc) {
    int i = blockIdx.x * blockDim.x + threadIdx.x;
    if (i < E) {
        int d = dst[i];
        int r = atomicAdd(&cursor[d], 1);
        ssrc[offsets[d] + r] = src[i];
    }
}

// ---------------- per-node online-softmax attention ----------------
// One wave per node. Lane l owns elements 4l..4l+3 (head = l>>3).
// kv layout: row s = [K(256 bf16) | V(256 bf16)], 1 KB per node.
// 8-edge unroll (16 gathers in flight) for memory-level parallelism.
__global__ __launch_bounds__(256) void attn_kernel(
    const unsigned short* __restrict__ qb, const unsigned short* __restrict__ kv,
    const int* __restrict__ offsets, const int* __restrict__ ssrc,
    unsigned short* __restrict__ attn, int N)
{
    const int node = blockIdx.x * 4 + (threadIdx.x >> 6);
    if (node >= N) return;
    const int lane = threadIdx.x & 63;

    ushort4 qu = *(const ushort4*)(qb + (size_t)node * D_MODEL + 4 * lane);
    const float sc = 0.17677669529663689f;  // 1/sqrt(32)
    float qx = bf2f(qu.x) * sc, qy = bf2f(qu.y) * sc,
          qz = bf2f(qu.z) * sc, qw = bf2f(qu.w) * sc;

    float m = -INFINITY, l = 0.f;
    float ax = 0.f, ay = 0.f, az = 0.f, aw = 0.f;

    const int e0 = offsets[node], e1 = offsets[node + 1];
    int e = e0;

    for (; e + 7 < e1; e += 8) {
        ushort4 K[8], V[8];
#pragma unroll
        for (int u = 0; u < 8; ++u) {
            const unsigned short* b = kv + (size_t)ssrc[e + u] * 512;
            K[u] = *(const ushort4*)(b + 4 * lane);
            V[u] = *(const ushort4*)(b + D_MODEL + 4 * lane);
        }
        float p[8];
#pragma unroll
        for (int u = 0; u < 8; ++u)
            p[u] = qx * bf2f(K[u].x) + qy * bf2f(K[u].y) + qz * bf2f(K[u].z) + qw * bf2f(K[u].w);
#pragma unroll
        for (int d = 1; d <= 4; d <<= 1)
#pragma unroll
            for (int u = 0; u < 8; ++u) p[u] += __shfl_xor(p[u], d);
        float mnew = m;
#pragma unroll
        for (int u = 0; u < 8; ++u) mnew = fmaxf(mnew, p[u]);
        const float alpha = __expf(m - mnew);   // 0 on first group (m=-inf)
        float w[8];
#pragma unroll
        for (int u = 0; u < 8; ++u) w[u] = __expf(p[u] - mnew);
        float sx = 0.f, sy = 0.f, sz = 0.f, sw = 0.f, sl = 0.f;
#pragma unroll
        for (int u = 0; u < 8; ++u) {
            sx += w[u] * bf2f(V[u].x);
            sy += w[u] * bf2f(V[u].y);
            sz += w[u] * bf2f(V[u].z);
            sw += w[u] * bf2f(V[u].w);
            sl += w[u];
        }
        ax = ax * alpha + sx; ay = ay * alpha + sy;
        az = az * alpha + sz; aw = aw * alpha + sw;
        l  = l * alpha + sl;
        m  = mnew;
    }
    for (; e < e1; ++e) {
        const unsigned short* b = kv + (size_t)ssrc[e] * 512;
        ushort4 ku = *(const ushort4*)(b + 4 * lane);
        ushort4 vu = *(const ushort4*)(b + D_MODEL + 4 * lane);
        float p = qx * bf2f(ku.x) + qy * bf2f(ku.y) + qz * bf2f(ku.z) + qw * bf2f(ku.w);
        p += __shfl_xor(p, 1);
        p += __shfl_xor(p, 2);
        p += __shfl_xor(p, 4);
        float mnew  = fmaxf(m, p);
        float alpha = __expf(m - mnew);
        float w     = __expf(p - mnew);
        ax = ax * alpha + w * bf2f(vu.x);
        ay = ay * alpha + w * bf2f(vu.y);
        az = az * alpha + w * bf2f(vu.z);
        aw = aw * alpha + w * bf2f(vu.w);
        l = l * alpha + w;
        m = mnew;
    }

    const float inv = (l > 0.f) ? 1.f / l : 0.f;  // deg-0 nodes -> zeros
    ushort4 o;
    o.x = f2bf_rne(ax * inv);
    o.y = f2bf_rne(ay * inv);
    o.z = f2bf_rne(az * inv);
    o.w = f2bf_rne(aw * inv);
    *(ushort4*)(attn + (size_t)node * D_MODEL + 4 * lane) = o;
}

// ---------------- launch ----------------
extern "C" void kernel_launch(void* const* d_in, const int* in_sizes, int n_in,
                              void* d_out, int out_size, void* d_ws, size_t ws_size,
                              hipStream_t stream)
{
    const float* query = (const float*)d_in[0];
    const float* key   = (const float*)d_in[1];
    const float* value = (const float*)d_in[2];
    const int*   edges = (const int*)d_in[3];
    const float* Wq = (const float*)d_in[4];
    const float* bq = (const float*)d_in[5];
    const float* Wk = (const float*)d_in[6];
    const float* bk = (const float*)d_in[7];
    const float* Wv = (const float*)d_in[8];
    const float* bv = (const float*)d_in[9];
    const float* Wo = (const float*)d_in[10];
    const float* bo = (const float*)d_in[11];
    float* out = (float*)d_out;

    const int N = in_sizes[0] / D_MODEL;
    const int E = in_sizes[3] / 2;
    const int* dst = edges;
    const int* src = edges + E;

    char* ws = (char*)d_ws;
    size_t off = 0;
    auto alloc = [&](size_t bytes) {
        void* p = ws + off;
        off += (bytes + 255) & ~(size_t)255;
        return p;
    };
    unsigned short* qbuf  = (unsigned short*)alloc((size_t)N * D_MODEL * 2);
    unsigned short* kvbuf = (unsigned short*)alloc((size_t)N * 2 * D_MODEL * 2); // K|V interleaved
    unsigned short* attnb = (unsigned short*)alloc((size_t)N * D_MODEL * 2);
    unsigned short* Wbuf  = (unsigned short*)alloc((size_t)4 * D_MODEL * D_MODEL * 2);
    int*            counts  = (int*)alloc((size_t)2 * N * 4);   // counts + cursor contiguous
    int*            offsets = (int*)alloc((size_t)(N + 1) * 4);
    int*            ssrc    = (int*)alloc((size_t)E * 4);
    int*            bsums   = (int*)alloc((size_t)256 * 4);

    hipMemsetAsync(counts, 0, (size_t)2 * N * 4, stream);

    conv_weights<<<(4 * 8192 + 255) / 256, 256, 0, stream>>>(Wq, Wk, Wv, Wo, Wbuf);

    const int mblocks = (N + 63) / 64;
    gemm_proj<0, 1><<<mblocks, 256, 0, stream>>>(query, Wbuf,                         bq, qbuf,  N, D_MODEL, 0);
    gemm_proj<0, 1><<<mblocks, 256, 0, stream>>>(key,   Wbuf + D_MODEL * D_MODEL,     bk, kvbuf, N, 2 * D_MODEL, 0);
    gemm_proj<0, 1><<<mblocks, 256, 0, stream>>>(value, Wbuf + 2 * D_MODEL * D_MODEL, bv, kvbuf, N, 2 * D_MODEL, D_MODEL);

    const int eblocks = (E + 255) / 256;
    hist_kernel<<<eblocks, 256, 0, stream>>>(dst, E, counts);

    const int G = (N + 256) / 256;  // ceil((N+1)/256)
    block_reduce_kernel<<<G, 256, 0, stream>>>(counts, N, bsums);
    scan_blocks_kernel<<<1, 256, 0, stream>>>(bsums, G);
    scan_write_kernel<<<G, 256, 0, stream>>>(counts, N, bsums, offsets);

    fill_kernel<<<eblocks, 256, 0, stream>>>(dst, src, E, offsets, counts + N, ssrc);
    attn_kernel<<<(N + 3) / 4, 256, 0, stream>>>(qbuf, kvbuf, offsets, ssrc, attnb, N);

    gemm_proj<1, 0><<<mblocks, 256, 0, stream>>>(attnb, Wbuf + 3 * D_MODEL * D_MODEL, bo, out, N, D_MODEL, 0);
}

// Round 5
// 394.808 us; speedup vs baseline: 1.5150x; 1.1771x over previous
//
#include <hip/hip_runtime.h>
#include <hip/hip_bf16.h>
#include <cstdint>

#define D_MODEL 256
#define NHEADS 8
#define DK 32
#define LDSPAD 8
#define LDSROW (D_MODEL + LDSPAD)   // 264 bf16 per LDS row

typedef float f32x4 __attribute__((ext_vector_type(4)));
typedef __bf16 bf16x8 __attribute__((ext_vector_type(8)));

__device__ __forceinline__ unsigned short f2bf_rne(float f) {
    unsigned int u = __float_as_uint(f);
    u += 0x7FFF + ((u >> 16) & 1);
    return (unsigned short)(u >> 16);
}
__device__ __forceinline__ float bf2f(unsigned short h) {
    return __uint_as_float(((unsigned int)h) << 16);
}

// ---------------- weight fp32 -> bf16, pre-swizzled into MFMA B-fragment order ---
// Layout: for weight w, fragment block (ntile 0..15, kk 0..7): 1 KB containing
// lane-major bf16x8: elem j of lane l = W[ntile*16 + (l&15)][kk*32 + (l>>4)*8 + j].
__global__ void conv_weights(const float* __restrict__ W0, const float* __restrict__ W1,
                             const float* __restrict__ W2, const float* __restrict__ W3,
                             unsigned short* __restrict__ out) {
    int i = blockIdx.x * blockDim.x + threadIdx.x;   // 4 * 16*8*64 = 32768 threads
    if (i >= 4 * 8192) return;
    const int w    = i >> 13;
    const int rem  = i & 8191;            // (ntile*8 + kk)*64 + lane
    const int lane = rem & 63;
    const int kk   = (rem >> 6) & 7;
    const int ntile= rem >> 9;
    const int row  = ntile * 16 + (lane & 15);
    const int col  = kk * 32 + (lane >> 4) * 8;
    const float* Wsrc = (w == 0) ? W0 : (w == 1) ? W1 : (w == 2) ? W2 : W3;
    const float* sp = Wsrc + (size_t)row * D_MODEL + col;
    float4 x0 = *(const float4*)sp;
    float4 x1 = *(const float4*)(sp + 4);
    unsigned short* dp = out + (size_t)w * D_MODEL * D_MODEL + (size_t)rem * 8;
    ushort4 o0, o1;
    o0.x = f2bf_rne(x0.x); o0.y = f2bf_rne(x0.y); o0.z = f2bf_rne(x0.z); o0.w = f2bf_rne(x0.w);
    o1.x = f2bf_rne(x1.x); o1.y = f2bf_rne(x1.y); o1.z = f2bf_rne(x1.z); o1.w = f2bf_rne(x1.w);
    *(ushort4*)dp = o0;
    *(ushort4*)(dp + 4) = o1;
}

// ---------------- merged QKV GEMM: 3 GEMMs in one dispatch -----------------------
// blockIdx.y in {0,1,2} selects (A, Wslice, bias, out) for q/k/v projections.
// BM=32 rows/block -> 1563*3 blocks (deep block pipeline hides latency).
// A staged via LDS (coalesced fp32 loads + cvt), B from pre-swizzled global.
// MFMA 16x16x32 bf16. D: col=lane&15, row=quad*4+reg.
__global__ __launch_bounds__(256, 4) void gemm_qkv(
    const float* __restrict__ Aq, const float* __restrict__ Ak, const float* __restrict__ Av,
    const unsigned short* __restrict__ Wsw,
    const float* __restrict__ bq, const float* __restrict__ bk, const float* __restrict__ bv,
    unsigned short* __restrict__ qbuf, unsigned short* __restrict__ kvbuf, int M)
{
    __shared__ __align__(16) unsigned short smem[32 * LDSROW];

    const int which = blockIdx.y;
    const float* A = (which == 0) ? Aq : (which == 1) ? Ak : Av;
    const float* bias = (which == 0) ? bq : (which == 1) ? bk : bv;
    const unsigned short* Wb = Wsw + (size_t)which * D_MODEL * D_MODEL;
    unsigned short* outp = (which == 0) ? qbuf : kvbuf;
    const int out_stride = (which == 0) ? D_MODEL : 2 * D_MODEL;
    const int out_off    = (which == 2) ? D_MODEL : 0;

    const int lane  = threadIdx.x & 63;
    const int wave  = threadIdx.x >> 6;
    const int m0    = blockIdx.x * 32;
    const int mrow  = lane & 15;
    const int quad  = lane >> 4;

    // ---- stage A tile (32 x 256 fp32) into LDS as bf16 ----
#pragma unroll
    for (int i = 0; i < 8; ++i) {
        const int g = i * 256 + threadIdx.x;     // float4 index
        const int r = g >> 6, c4 = g & 63;
        const int grow = min(m0 + r, M - 1);
        float4 x = *(const float4*)(A + (size_t)grow * D_MODEL + c4 * 4);
        ushort4 o;
        o.x = f2bf_rne(x.x); o.y = f2bf_rne(x.y);
        o.z = f2bf_rne(x.z); o.w = f2bf_rne(x.w);
        *(ushort4*)(smem + r * LDSROW + c4 * 4) = o;
    }
    __syncthreads();

    f32x4 acc[2][4] = {};

#pragma unroll
    for (int kk = 0; kk < 8; ++kk) {
        bf16x8 afr[2];
#pragma unroll
        for (int mi = 0; mi < 2; ++mi)
            afr[mi] = *(const bf16x8*)(smem + (mi * 16 + mrow) * LDSROW + kk * 32 + quad * 8);
        bf16x8 bfr[4];
#pragma unroll
        for (int ni = 0; ni < 4; ++ni) {
            const int ntile = wave * 4 + ni;
            bfr[ni] = *(const bf16x8*)(Wb + ((size_t)(ntile * 8 + kk) * 64 + lane) * 8);
        }
#pragma unroll
        for (int mi = 0; mi < 2; ++mi)
#pragma unroll
            for (int ni = 0; ni < 4; ++ni)
                acc[mi][ni] = __builtin_amdgcn_mfma_f32_16x16x32_bf16(
                    afr[mi], bfr[ni], acc[mi][ni], 0, 0, 0);
    }

#pragma unroll
    for (int ni = 0; ni < 4; ++ni) {
        const int col = wave * 64 + ni * 16 + mrow;
        const float bv2 = bias[col];
#pragma unroll
        for (int mi = 0; mi < 2; ++mi) {
#pragma unroll
            for (int r = 0; r < 4; ++r) {
                const int row = m0 + mi * 16 + quad * 4 + r;
                if (row < M)
                    outp[(size_t)row * out_stride + out_off + col] =
                        f2bf_rne(acc[mi][ni][r] + bv2);
            }
        }
    }
}

// ---------------- output GEMM: out[M,256] = attn(bf16) @ Wo^T + bo (fp32) --------
__global__ __launch_bounds__(256, 4) void gemm_out(
    const unsigned short* __restrict__ Ab, const unsigned short* __restrict__ Wb,
    const float* __restrict__ bias, float* __restrict__ outp, int M)
{
    __shared__ __align__(16) unsigned short smem[32 * LDSROW];

    const int lane  = threadIdx.x & 63;
    const int wave  = threadIdx.x >> 6;
    const int m0    = blockIdx.x * 32;
    const int mrow  = lane & 15;
    const int quad  = lane >> 4;

    // ---- stage A tile (32 x 256 bf16) into LDS ----
#pragma unroll
    for (int i = 0; i < 4; ++i) {
        const int g = i * 256 + threadIdx.x;     // ushort8 index
        const int r = g >> 5, c8 = g & 31;
        const int grow = min(m0 + r, M - 1);
        bf16x8 x = *(const bf16x8*)(Ab + (size_t)grow * D_MODEL + c8 * 8);
        *(bf16x8*)(smem + r * LDSROW + c8 * 8) = x;
    }
    __syncthreads();

    f32x4 acc[2][4] = {};

#pragma unroll
    for (int kk = 0; kk < 8; ++kk) {
        bf16x8 afr[2];
#pragma unroll
        for (int mi = 0; mi < 2; ++mi)
            afr[mi] = *(const bf16x8*)(smem + (mi * 16 + mrow) * LDSROW + kk * 32 + quad * 8);
        bf16x8 bfr[4];
#pragma unroll
        for (int ni = 0; ni < 4; ++ni) {
            const int ntile = wave * 4 + ni;
            bfr[ni] = *(const bf16x8*)(Wb + ((size_t)(ntile * 8 + kk) * 64 + lane) * 8);
        }
#pragma unroll
        for (int mi = 0; mi < 2; ++mi)
#pragma unroll
            for (int ni = 0; ni < 4; ++ni)
                acc[mi][ni] = __builtin_amdgcn_mfma_f32_16x16x32_bf16(
                    afr[mi], bfr[ni], acc[mi][ni], 0, 0, 0);
    }

#pragma unroll
    for (int ni = 0; ni < 4; ++ni) {
        const int col = wave * 64 + ni * 16 + mrow;
        const float bv2 = bias[col];
#pragma unroll
        for (int mi = 0; mi < 2; ++mi) {
#pragma unroll
            for (int r = 0; r < 4; ++r) {
                const int row = m0 + mi * 16 + quad * 4 + r;
                if (row < M)
                    outp[(size_t)row * D_MODEL + col] = acc[mi][ni][r] + bv2;
            }
        }
    }
}

// ---------------- CSR construction ----------------
__global__ void hist_kernel(const int* __restrict__ dst, int E, int* __restrict__ counts) {
    int i = blockIdx.x * blockDim.x + threadIdx.x;
    if (i < E) atomicAdd(&counts[dst[i]], 1);
}

__global__ void block_reduce_kernel(const int* __restrict__ counts, int N,
                                    int* __restrict__ blockSums) {
    const int g = blockIdx.x * 256 + threadIdx.x;
    int v = (g < N) ? counts[g] : 0;
#pragma unroll
    for (int d = 1; d < 64; d <<= 1) v += __shfl_xor(v, d);
    __shared__ int ws[4];
    if ((threadIdx.x & 63) == 0) ws[threadIdx.x >> 6] = v;
    __syncthreads();
    if (threadIdx.x == 0) blockSums[blockIdx.x] = ws[0] + ws[1] + ws[2] + ws[3];
}

__global__ void scan_blocks_kernel(int* __restrict__ blockSums, int G) {
    __shared__ int sh[256];
    const int t = threadIdx.x;
    int v = (t < G) ? blockSums[t] : 0;
    sh[t] = v;
    __syncthreads();
#pragma unroll
    for (int off = 1; off < 256; off <<= 1) {
        int add = (t >= off) ? sh[t - off] : 0;
        __syncthreads();
        sh[t] += add;
        __syncthreads();
    }
    if (t < G) blockSums[t] = sh[t] - v;   // exclusive
}

__global__ void scan_write_kernel(const int* __restrict__ counts, int N,
                                  const int* __restrict__ blockOffsets,
                                  int* __restrict__ offsets) {
    const int g = blockIdx.x * 256 + threadIdx.x;
    const int t = threadIdx.x;
    int v = (g < N) ? counts[g] : 0;
    __shared__ int sh[256];
    sh[t] = v;
    __syncthreads();
#pragma unroll
    for (int off = 1; off < 256; off <<= 1) {
        int add = (t >= off) ? sh[t - off] : 0;
        __syncthreads();
        sh[t] += add;
        __syncthreads();
    }
    if (g <= N) offsets[g] = sh[t] - v + blockOffsets[blockIdx.x];
}

__global__ void fill_kernel(const int* __restrict__ dst, const int* __restrict__ src, int E,
                            const int* __restrict__ offsets, int* __restrict__ cursor,
                            int* __restrict__ ssrc) {
    int i = blockIdx.x * blockDim.x + threadIdx.x;
    if (i < E) {
        int d = dst[i];
        int r = atomicAdd(&cursor[d], 1);
        ssrc[offsets[d] + r] = src[i];
    }
}

// ---------------- per-node online-softmax attention (R3 4-unroll version) --------
// One wave per node. Lane l owns elements 4l..4l+3 (head = l>>3).
// kv layout: row s = [K(256 bf16) | V(256 bf16)], 1 KB per node.
__global__ __launch_bounds__(256) void attn_kernel(
    const unsigned short* __restrict__ qb, const unsigned short* __restrict__ kv,
    const int* __restrict__ offsets, const int* __restrict__ ssrc,
    unsigned short* __restrict__ attn, int N)
{
    const int node = blockIdx.x * 4 + (threadIdx.x >> 6);
    if (node >= N) return;
    const int lane = threadIdx.x & 63;

    ushort4 qu = *(const ushort4*)(qb + (size_t)node * D_MODEL + 4 * lane);
    const float sc = 0.17677669529663689f;  // 1/sqrt(32)
    float qx = bf2f(qu.x) * sc, qy = bf2f(qu.y) * sc,
          qz = bf2f(qu.z) * sc, qw = bf2f(qu.w) * sc;

    float m = -INFINITY, l = 0.f;
    float ax = 0.f, ay = 0.f, az = 0.f, aw = 0.f;

    const int e0 = offsets[node], e1 = offsets[node + 1];
    int e = e0;

    for (; e + 3 < e1; e += 4) {
        int s0 = ssrc[e], s1 = ssrc[e + 1], s2 = ssrc[e + 2], s3 = ssrc[e + 3];
        const unsigned short* b0 = kv + (size_t)s0 * 512;
        const unsigned short* b1 = kv + (size_t)s1 * 512;
        const unsigned short* b2 = kv + (size_t)s2 * 512;
        const unsigned short* b3 = kv + (size_t)s3 * 512;
        ushort4 k0 = *(const ushort4*)(b0 + 4 * lane);
        ushort4 k1 = *(const ushort4*)(b1 + 4 * lane);
        ushort4 k2 = *(const ushort4*)(b2 + 4 * lane);
        ushort4 k3 = *(const ushort4*)(b3 + 4 * lane);
        ushort4 v0 = *(const ushort4*)(b0 + D_MODEL + 4 * lane);
        ushort4 v1 = *(const ushort4*)(b1 + D_MODEL + 4 * lane);
        ushort4 v2 = *(const ushort4*)(b2 + D_MODEL + 4 * lane);
        ushort4 v3 = *(const ushort4*)(b3 + D_MODEL + 4 * lane);

        float p0 = qx * bf2f(k0.x) + qy * bf2f(k0.y) + qz * bf2f(k0.z) + qw * bf2f(k0.w);
        float p1 = qx * bf2f(k1.x) + qy * bf2f(k1.y) + qz * bf2f(k1.z) + qw * bf2f(k1.w);
        float p2 = qx * bf2f(k2.x) + qy * bf2f(k2.y) + qz * bf2f(k2.z) + qw * bf2f(k2.w);
        float p3 = qx * bf2f(k3.x) + qy * bf2f(k3.y) + qz * bf2f(k3.z) + qw * bf2f(k3.w);
#pragma unroll
        for (int d = 1; d <= 4; d <<= 1) {
            p0 += __shfl_xor(p0, d);
            p1 += __shfl_xor(p1, d);
            p2 += __shfl_xor(p2, d);
            p3 += __shfl_xor(p3, d);
        }
        float mnew = fmaxf(fmaxf(fmaxf(m, p0), fmaxf(p1, p2)), p3);
        float alpha = __expf(m - mnew);     // 0 on first group (m=-inf)
        float w0 = __expf(p0 - mnew), w1 = __expf(p1 - mnew);
        float w2 = __expf(p2 - mnew), w3 = __expf(p3 - mnew);
        ax = ax * alpha + w0 * bf2f(v0.x) + w1 * bf2f(v1.x) + w2 * bf2f(v2.x) + w3 * bf2f(v3.x);
        ay = ay * alpha + w0 * bf2f(v0.y) + w1 * bf2f(v1.y) + w2 * bf2f(v2.y) + w3 * bf2f(v3.y);
        az = az * alpha + w0 * bf2f(v0.z) + w1 * bf2f(v1.z) + w2 * bf2f(v2.z) + w3 * bf2f(v3.z);
        aw = aw * alpha + w0 * bf2f(v0.w) + w1 * bf2f(v1.w) + w2 * bf2f(v2.w) + w3 * bf2f(v3.w);
        l = l * alpha + w0 + w1 + w2 + w3;
        m = mnew;
    }
    for (; e < e1; ++e) {
        int s = ssrc[e];
        const unsigned short* b = kv + (size_t)s * 512;
        ushort4 ku = *(const ushort4*)(b + 4 * lane);
        ushort4 vu = *(const ushort4*)(b + D_MODEL + 4 * lane);
        float p = qx * bf2f(ku.x) + qy * bf2f(ku.y) + qz * bf2f(ku.z) + qw * bf2f(ku.w);
        p += __shfl_xor(p, 1);
        p += __shfl_xor(p, 2);
        p += __shfl_xor(p, 4);
        float mnew  = fmaxf(m, p);
        float alpha = __expf(m - mnew);
        float w     = __expf(p - mnew);
        ax = ax * alpha + w * bf2f(vu.x);
        ay = ay * alpha + w * bf2f(vu.y);
        az = az * alpha + w * bf2f(vu.z);
        aw = aw * alpha + w * bf2f(vu.w);
        l = l * alpha + w;
        m = mnew;
    }

    const float inv = (l > 0.f) ? 1.f / l : 0.f;  // deg-0 nodes -> zeros
    ushort4 o;
    o.x = f2bf_rne(ax * inv);
    o.y = f2bf_rne(ay * inv);
    o.z = f2bf_rne(az * inv);
    o.w = f2bf_rne(aw * inv);
    *(ushort4*)(attn + (size_t)node * D_MODEL + 4 * lane) = o;
}

// ---------------- launch ----------------
extern "C" void kernel_launch(void* const* d_in, const int* in_sizes, int n_in,
                              void* d_out, int out_size, void* d_ws, size_t ws_size,
                              hipStream_t stream)
{
    const float* query = (const float*)d_in[0];
    const float* key   = (const float*)d_in[1];
    const float* value = (const float*)d_in[2];
    const int*   edges = (const int*)d_in[3];
    const float* Wq = (const float*)d_in[4];
    const float* bq = (const float*)d_in[5];
    const float* Wk = (const float*)d_in[6];
    const float* bk = (const float*)d_in[7];
    const float* Wv = (const float*)d_in[8];
    const float* bv = (const float*)d_in[9];
    const float* Wo = (const float*)d_in[10];
    const float* bo = (const float*)d_in[11];
    float* out = (float*)d_out;

    const int N = in_sizes[0] / D_MODEL;
    const int E = in_sizes[3] / 2;
    const int* dst = edges;
    const int* src = edges + E;

    char* ws = (char*)d_ws;
    size_t off = 0;
    auto alloc = [&](size_t bytes) {
        void* p = ws + off;
        off += (bytes + 255) & ~(size_t)255;
        return p;
    };
    unsigned short* qbuf  = (unsigned short*)alloc((size_t)N * D_MODEL * 2);
    unsigned short* kvbuf = (unsigned short*)alloc((size_t)N * 2 * D_MODEL * 2); // K|V interleaved
    unsigned short* attnb = (unsigned short*)alloc((size_t)N * D_MODEL * 2);
    unsigned short* Wbuf  = (unsigned short*)alloc((size_t)4 * D_MODEL * D_MODEL * 2);
    int*            counts  = (int*)alloc((size_t)2 * N * 4);   // counts + cursor contiguous
    int*            offsets = (int*)alloc((size_t)(N + 1) * 4);
    int*            ssrc    = (int*)alloc((size_t)E * 4);
    int*            bsums   = (int*)alloc((size_t)256 * 4);

    hipMemsetAsync(counts, 0, (size_t)2 * N * 4, stream);

    conv_weights<<<(4 * 8192 + 255) / 256, 256, 0, stream>>>(Wq, Wk, Wv, Wo, Wbuf);

    const int mb32 = (N + 31) / 32;
    gemm_qkv<<<dim3(mb32, 3), 256, 0, stream>>>(query, key, value, Wbuf,
                                                bq, bk, bv, qbuf, kvbuf, N);

    const int eblocks = (E + 255) / 256;
    hist_kernel<<<eblocks, 256, 0, stream>>>(dst, E, counts);

    const int G = (N + 256) / 256;  // ceil((N+1)/256)
    block_reduce_kernel<<<G, 256, 0, stream>>>(counts, N, bsums);
    scan_blocks_kernel<<<1, 256, 0, stream>>>(bsums, G);
    scan_write_kernel<<<G, 256, 0, stream>>>(counts, N, bsums, offsets);

    fill_kernel<<<eblocks, 256, 0, stream>>>(dst, src, E, offsets, counts + N, ssrc);
    attn_kernel<<<(N + 3) / 4, 256, 0, stream>>>(qbuf, kvbuf, offsets, ssrc, attnb, N);

    gemm_out<<<mb32, 256, 0, stream>>>(attnb, Wbuf + 3 * D_MODEL * D_MODEL, bo, out, N);
}

// Round 6
// 389.171 us; speedup vs baseline: 1.5370x; 1.0145x over previous
//
#include <hip/hip_runtime.h>
#include <hip/hip_bf16.h>
#include <cstdint>

#define D_MODEL 256
#define NHEADS 8
#define DK 32
#define LDSPAD 8
#define LDSROW (D_MODEL + LDSPAD)   // 264 bf16 per LDS row

typedef float f32x4 __attribute__((ext_vector_type(4)));
typedef __bf16 bf16x8 __attribute__((ext_vector_type(8)));

__device__ __forceinline__ unsigned short f2bf_rne(float f) {
    unsigned int u = __float_as_uint(f);
    u += 0x7FFF + ((u >> 16) & 1);
    return (unsigned short)(u >> 16);
}
__device__ __forceinline__ float bf2f(unsigned short h) {
    return __uint_as_float(((unsigned int)h) << 16);
}

// ---------------- weight fp32 -> bf16, pre-swizzled into MFMA B-fragment order ---
// Layout: for weight w, fragment block (ntile 0..15, kk 0..7): 1 KB containing
// lane-major bf16x8: elem j of lane l = W[ntile*16 + (l&15)][kk*32 + (l>>4)*8 + j].
__global__ void conv_weights(const float* __restrict__ W0, const float* __restrict__ W1,
                             const float* __restrict__ W2, const float* __restrict__ W3,
                             unsigned short* __restrict__ out) {
    int i = blockIdx.x * blockDim.x + threadIdx.x;   // 4 * 16*8*64 = 32768 threads
    if (i >= 4 * 8192) return;
    const int w    = i >> 13;
    const int rem  = i & 8191;            // (ntile*8 + kk)*64 + lane
    const int lane = rem & 63;
    const int kk   = (rem >> 6) & 7;
    const int ntile= rem >> 9;
    const int row  = ntile * 16 + (lane & 15);
    const int col  = kk * 32 + (lane >> 4) * 8;
    const float* Wsrc = (w == 0) ? W0 : (w == 1) ? W1 : (w == 2) ? W2 : W3;
    const float* sp = Wsrc + (size_t)row * D_MODEL + col;
    float4 x0 = *(const float4*)sp;
    float4 x1 = *(const float4*)(sp + 4);
    unsigned short* dp = out + (size_t)w * D_MODEL * D_MODEL + (size_t)rem * 8;
    ushort4 o0, o1;
    o0.x = f2bf_rne(x0.x); o0.y = f2bf_rne(x0.y); o0.z = f2bf_rne(x0.z); o0.w = f2bf_rne(x0.w);
    o1.x = f2bf_rne(x1.x); o1.y = f2bf_rne(x1.y); o1.z = f2bf_rne(x1.z); o1.w = f2bf_rne(x1.w);
    *(ushort4*)dp = o0;
    *(ushort4*)(dp + 4) = o1;
}

// ---------------- merged QKV GEMM: 3 GEMMs in one dispatch -----------------------
// blockIdx.y in {0,1,2} selects (A, Wslice, bias, out) for q/k/v projections.
// BM=32 rows/block. A staged via LDS; B from pre-swizzled global (L2-resident).
// Epilogue: bf16 accumulators bounce through LDS so global stores are 16 B/lane
// coalesced (direct 2 B stores caused ~1.85x HBM write amplification).
// MFMA 16x16x32 bf16. D: col=lane&15, row=quad*4+reg.
__global__ __launch_bounds__(256, 8) void gemm_qkv(
    const float* __restrict__ Aq, const float* __restrict__ Ak, const float* __restrict__ Av,
    const unsigned short* __restrict__ Wsw,
    const float* __restrict__ bq, const float* __restrict__ bk, const float* __restrict__ bv,
    unsigned short* __restrict__ qbuf, unsigned short* __restrict__ kvbuf, int M)
{
    __shared__ __align__(16) unsigned short smem[32 * LDSROW];

    const int which = blockIdx.y;
    const float* A = (which == 0) ? Aq : (which == 1) ? Ak : Av;
    const float* bias = (which == 0) ? bq : (which == 1) ? bk : bv;
    const unsigned short* Wb = Wsw + (size_t)which * D_MODEL * D_MODEL;
    unsigned short* outp = (which == 0) ? qbuf : kvbuf;
    const int out_stride = (which == 0) ? D_MODEL : 2 * D_MODEL;
    const int out_off    = (which == 2) ? D_MODEL : 0;

    const int lane  = threadIdx.x & 63;
    const int wave  = threadIdx.x >> 6;
    const int m0    = blockIdx.x * 32;
    const int mrow  = lane & 15;
    const int quad  = lane >> 4;

    // ---- stage A tile (32 x 256 fp32) into LDS as bf16 ----
#pragma unroll
    for (int i = 0; i < 8; ++i) {
        const int g = i * 256 + threadIdx.x;     // float4 index
        const int r = g >> 6, c4 = g & 63;
        const int grow = min(m0 + r, M - 1);
        float4 x = *(const float4*)(A + (size_t)grow * D_MODEL + c4 * 4);
        ushort4 o;
        o.x = f2bf_rne(x.x); o.y = f2bf_rne(x.y);
        o.z = f2bf_rne(x.z); o.w = f2bf_rne(x.w);
        *(ushort4*)(smem + r * LDSROW + c4 * 4) = o;
    }
    __syncthreads();

    f32x4 acc[2][4] = {};

#pragma unroll
    for (int kk = 0; kk < 8; ++kk) {
        bf16x8 afr[2];
#pragma unroll
        for (int mi = 0; mi < 2; ++mi)
            afr[mi] = *(const bf16x8*)(smem + (mi * 16 + mrow) * LDSROW + kk * 32 + quad * 8);
        bf16x8 bfr[4];
#pragma unroll
        for (int ni = 0; ni < 4; ++ni) {
            const int ntile = wave * 4 + ni;
            bfr[ni] = *(const bf16x8*)(Wb + ((size_t)(ntile * 8 + kk) * 64 + lane) * 8);
        }
#pragma unroll
        for (int mi = 0; mi < 2; ++mi)
#pragma unroll
            for (int ni = 0; ni < 4; ++ni)
                acc[mi][ni] = __builtin_amdgcn_mfma_f32_16x16x32_bf16(
                    afr[mi], bfr[ni], acc[mi][ni], 0, 0, 0);
    }

    // ---- epilogue: bias + bf16, transpose through LDS, coalesced 16B stores ----
    __syncthreads();   // all waves finished reading A-tile from smem
#pragma unroll
    for (int ni = 0; ni < 4; ++ni) {
        const int col = wave * 64 + ni * 16 + mrow;
        const float bv2 = bias[col];
#pragma unroll
        for (int mi = 0; mi < 2; ++mi)
#pragma unroll
            for (int r = 0; r < 4; ++r) {
                const int rl = mi * 16 + quad * 4 + r;
                smem[rl * LDSROW + col] = f2bf_rne(acc[mi][ni][r] + bv2);
            }
    }
    __syncthreads();
#pragma unroll
    for (int i = 0; i < 4; ++i) {
        const int g = i * 256 + threadIdx.x;     // ushort8 chunk index
        const int r = g >> 5, c8 = g & 31;
        const int grow = m0 + r;
        if (grow < M) {
            bf16x8 x = *(const bf16x8*)(smem + r * LDSROW + c8 * 8);
            *(bf16x8*)(outp + (size_t)grow * out_stride + out_off + c8 * 8) = x;
        }
    }
}

// ---------------- output GEMM: out[M,256] = attn(bf16) @ Wo^T + bo (fp32) --------
// fp32 stores are 64 B/16-lane segments (sector-aligned) -> direct stores OK.
__global__ __launch_bounds__(256, 8) void gemm_out(
    const unsigned short* __restrict__ Ab, const unsigned short* __restrict__ Wb,
    const float* __restrict__ bias, float* __restrict__ outp, int M)
{
    __shared__ __align__(16) unsigned short smem[32 * LDSROW];

    const int lane  = threadIdx.x & 63;
    const int wave  = threadIdx.x >> 6;
    const int m0    = blockIdx.x * 32;
    const int mrow  = lane & 15;
    const int quad  = lane >> 4;

    // ---- stage A tile (32 x 256 bf16) into LDS ----
#pragma unroll
    for (int i = 0; i < 4; ++i) {
        const int g = i * 256 + threadIdx.x;     // ushort8 index
        const int r = g >> 5, c8 = g & 31;
        const int grow = min(m0 + r, M - 1);
        bf16x8 x = *(const bf16x8*)(Ab + (size_t)grow * D_MODEL + c8 * 8);
        *(bf16x8*)(smem + r * LDSROW + c8 * 8) = x;
    }
    __syncthreads();

    f32x4 acc[2][4] = {};

#pragma unroll
    for (int kk = 0; kk < 8; ++kk) {
        bf16x8 afr[2];
#pragma unroll
        for (int mi = 0; mi < 2; ++mi)
            afr[mi] = *(const bf16x8*)(smem + (mi * 16 + mrow) * LDSROW + kk * 32 + quad * 8);
        bf16x8 bfr[4];
#pragma unroll
        for (int ni = 0; ni < 4; ++ni) {
            const int ntile = wave * 4 + ni;
            bfr[ni] = *(const bf16x8*)(Wb + ((size_t)(ntile * 8 + kk) * 64 + lane) * 8);
        }
#pragma unroll
        for (int mi = 0; mi < 2; ++mi)
#pragma unroll
            for (int ni = 0; ni < 4; ++ni)
                acc[mi][ni] = __builtin_amdgcn_mfma_f32_16x16x32_bf16(
                    afr[mi], bfr[ni], acc[mi][ni], 0, 0, 0);
    }

#pragma unroll
    for (int ni = 0; ni < 4; ++ni) {
        const int col = wave * 64 + ni * 16 + mrow;
        const float bv2 = bias[col];
#pragma unroll
        for (int mi = 0; mi < 2; ++mi) {
#pragma unroll
            for (int r = 0; r < 4; ++r) {
                const int row = m0 + mi * 16 + quad * 4 + r;
                if (row < M)
                    outp[(size_t)row * D_MODEL + col] = acc[mi][ni][r] + bv2;
            }
        }
    }
}

// ---------------- CSR construction ----------------
__global__ void hist_kernel(const int* __restrict__ dst, int E, int* __restrict__ counts) {
    int i = blockIdx.x * blockDim.x + threadIdx.x;
    if (i < E) atomicAdd(&counts[dst[i]], 1);
}

__global__ void block_reduce_kernel(const int* __restrict__ counts, int N,
                                    int* __restrict__ blockSums) {
    const int g = blockIdx.x * 256 + threadIdx.x;
    int v = (g < N) ? counts[g] : 0;
#pragma unroll
    for (int d = 1; d < 64; d <<= 1) v += __shfl_xor(v, d);
    __shared__ int ws[4];
    if ((threadIdx.x & 63) == 0) ws[threadIdx.x >> 6] = v;
    __syncthreads();
    if (threadIdx.x == 0) blockSums[blockIdx.x] = ws[0] + ws[1] + ws[2] + ws[3];
}

__global__ void scan_blocks_kernel(int* __restrict__ blockSums, int G) {
    __shared__ int sh[256];
    const int t = threadIdx.x;
    int v = (t < G) ? blockSums[t] : 0;
    sh[t] = v;
    __syncthreads();
#pragma unroll
    for (int off = 1; off < 256; off <<= 1) {
        int add = (t >= off) ? sh[t - off] : 0;
        __syncthreads();
        sh[t] += add;
        __syncthreads();
    }
    if (t < G) blockSums[t] = sh[t] - v;   // exclusive
}

__global__ void scan_write_kernel(const int* __restrict__ counts, int N,
                                  const int* __restrict__ blockOffsets,
                                  int* __restrict__ offsets) {
    const int g = blockIdx.x * 256 + threadIdx.x;
    const int t = threadIdx.x;
    int v = (g < N) ? counts[g] : 0;
    __shared__ int sh[256];
    sh[t] = v;
    __syncthreads();
#pragma unroll
    for (int off = 1; off < 256; off <<= 1) {
        int add = (t >= off) ? sh[t - off] : 0;
        __syncthreads();
        sh[t] += add;
        __syncthreads();
    }
    if (g <= N) offsets[g] = sh[t] - v + blockOffsets[blockIdx.x];
}

__global__ void fill_kernel(const int* __restrict__ dst, const int* __restrict__ src, int E,
                            const int* __restrict__ offsets, int* __restrict__ cursor,
                            int* __restrict__ ssrc) {
    int i = blockIdx.x * blockDim.x + threadIdx.x;
    if (i < E) {
        int d = dst[i];
        int r = atomicAdd(&cursor[d], 1);
        ssrc[offsets[d] + r] = src[i];
    }
}

// ---------------- per-node online-softmax attention ----------------
// One wave per node. Lane l owns elements 4l..4l+3 (head = l>>3).
// kv layout: row s = [K(256 bf16) | V(256 bf16)], 1 KB per node.
__global__ __launch_bounds__(256) void attn_kernel(
    const unsigned short* __restrict__ qb, const unsigned short* __restrict__ kv,
    const int* __restrict__ offsets, const int* __restrict__ ssrc,
    unsigned short* __restrict__ attn, int N)
{
    const int node = blockIdx.x * 4 + (threadIdx.x >> 6);
    if (node >= N) return;
    const int lane = threadIdx.x & 63;

    ushort4 qu = *(const ushort4*)(qb + (size_t)node * D_MODEL + 4 * lane);
    const float sc = 0.17677669529663689f;  // 1/sqrt(32)
    float qx = bf2f(qu.x) * sc, qy = bf2f(qu.y) * sc,
          qz = bf2f(qu.z) * sc, qw = bf2f(qu.w) * sc;

    float m = -INFINITY, l = 0.f;
    float ax = 0.f, ay = 0.f, az = 0.f, aw = 0.f;

    const int e0 = offsets[node], e1 = offsets[node + 1];
    int e = e0;

    for (; e + 3 < e1; e += 4) {
        int s0 = ssrc[e], s1 = ssrc[e + 1], s2 = ssrc[e + 2], s3 = ssrc[e + 3];
        const unsigned short* b0 = kv + (size_t)s0 * 512;
        const unsigned short* b1 = kv + (size_t)s1 * 512;
        const unsigned short* b2 = kv + (size_t)s2 * 512;
        const unsigned short* b3 = kv + (size_t)s3 * 512;
        ushort4 k0 = *(const ushort4*)(b0 + 4 * lane);
        ushort4 k1 = *(const ushort4*)(b1 + 4 * lane);
        ushort4 k2 = *(const ushort4*)(b2 + 4 * lane);
        ushort4 k3 = *(const ushort4*)(b3 + 4 * lane);
        ushort4 v0 = *(const ushort4*)(b0 + D_MODEL + 4 * lane);
        ushort4 v1 = *(const ushort4*)(b1 + D_MODEL + 4 * lane);
        ushort4 v2 = *(const ushort4*)(b2 + D_MODEL + 4 * lane);
        ushort4 v3 = *(const ushort4*)(b3 + D_MODEL + 4 * lane);

        float p0 = qx * bf2f(k0.x) + qy * bf2f(k0.y) + qz * bf2f(k0.z) + qw * bf2f(k0.w);
        float p1 = qx * bf2f(k1.x) + qy * bf2f(k1.y) + qz * bf2f(k1.z) + qw * bf2f(k1.w);
        float p2 = qx * bf2f(k2.x) + qy * bf2f(k2.y) + qz * bf2f(k2.z) + qw * bf2f(k2.w);
        float p3 = qx * bf2f(k3.x) + qy * bf2f(k3.y) + qz * bf2f(k3.z) + qw * bf2f(k3.w);
#pragma unroll
        for (int d = 1; d <= 4; d <<= 1) {
            p0 += __shfl_xor(p0, d);
            p1 += __shfl_xor(p1, d);
            p2 += __shfl_xor(p2, d);
            p3 += __shfl_xor(p3, d);
        }
        float mnew = fmaxf(fmaxf(fmaxf(m, p0), fmaxf(p1, p2)), p3);
        float alpha = __expf(m - mnew);     // 0 on first group (m=-inf)
        float w0 = __expf(p0 - mnew), w1 = __expf(p1 - mnew);
        float w2 = __expf(p2 - mnew), w3 = __expf(p3 - mnew);
        ax = ax * alpha + w0 * bf2f(v0.x) + w1 * bf2f(v1.x) + w2 * bf2f(v2.x) + w3 * bf2f(v3.x);
        ay = ay * alpha + w0 * bf2f(v0.y) + w1 * bf2f(v1.y) + w2 * bf2f(v2.y) + w3 * bf2f(v3.y);
        az = az * alpha + w0 * bf2f(v0.z) + w1 * bf2f(v1.z) + w2 * bf2f(v2.z) + w3 * bf2f(v3.z);
        aw = aw * alpha + w0 * bf2f(v0.w) + w1 * bf2f(v1.w) + w2 * bf2f(v2.w) + w3 * bf2f(v3.w);
        l = l * alpha + w0 + w1 + w2 + w3;
        m = mnew;
    }
    for (; e < e1; ++e) {
        int s = ssrc[e];
        const unsigned short* b = kv + (size_t)s * 512;
        ushort4 ku = *(const ushort4*)(b + 4 * lane);
        ushort4 vu = *(const ushort4*)(b + D_MODEL + 4 * lane);
        float p = qx * bf2f(ku.x) + qy * bf2f(ku.y) + qz * bf2f(ku.z) + qw * bf2f(ku.w);
        p += __shfl_xor(p, 1);
        p += __shfl_xor(p, 2);
        p += __shfl_xor(p, 4);
        float mnew  = fmaxf(m, p);
        float alpha = __expf(m - mnew);
        float w     = __expf(p - mnew);
        ax = ax * alpha + w * bf2f(vu.x);
        ay = ay * alpha + w * bf2f(vu.y);
        az = az * alpha + w * bf2f(vu.z);
        aw = aw * alpha + w * bf2f(vu.w);
        l = l * alpha + w;
        m = mnew;
    }

    const float inv = (l > 0.f) ? 1.f / l : 0.f;  // deg-0 nodes -> zeros
    ushort4 o;
    o.x = f2bf_rne(ax * inv);
    o.y = f2bf_rne(ay * inv);
    o.z = f2bf_rne(az * inv);
    o.w = f2bf_rne(aw * inv);
    *(ushort4*)(attn + (size_t)node * D_MODEL + 4 * lane) = o;
}

// ---------------- launch ----------------
extern "C" void kernel_launch(void* const* d_in, const int* in_sizes, int n_in,
                              void* d_out, int out_size, void* d_ws, size_t ws_size,
                              hipStream_t stream)
{
    const float* query = (const float*)d_in[0];
    const float* key   = (const float*)d_in[1];
    const float* value = (const float*)d_in[2];
    const int*   edges = (const int*)d_in[3];
    const float* Wq = (const float*)d_in[4];
    const float* bq = (const float*)d_in[5];
    const float* Wk = (const float*)d_in[6];
    const float* bk = (const float*)d_in[7];
    const float* Wv = (const float*)d_in[8];
    const float* bv = (const float*)d_in[9];
    const float* Wo = (const float*)d_in[10];
    const float* bo = (const float*)d_in[11];
    float* out = (float*)d_out;

    const int N = in_sizes[0] / D_MODEL;
    const int E = in_sizes[3] / 2;
    const int* dst = edges;
    const int* src = edges + E;

    char* ws = (char*)d_ws;
    size_t off = 0;
    auto alloc = [&](size_t bytes) {
        void* p = ws + off;
        off += (bytes + 255) & ~(size_t)255;
        return p;
    };
    unsigned short* qbuf  = (unsigned short*)alloc((size_t)N * D_MODEL * 2);
    unsigned short* kvbuf = (unsigned short*)alloc((size_t)N * 2 * D_MODEL * 2); // K|V interleaved
    unsigned short* attnb = (unsigned short*)alloc((size_t)N * D_MODEL * 2);
    unsigned short* Wbuf  = (unsigned short*)alloc((size_t)4 * D_MODEL * D_MODEL * 2);
    int*            counts  = (int*)alloc((size_t)2 * N * 4);   // counts + cursor contiguous
    int*            offsets = (int*)alloc((size_t)(N + 1) * 4);
    int*            ssrc    = (int*)alloc((size_t)E * 4);
    int*            bsums   = (int*)alloc((size_t)256 * 4);

    hipMemsetAsync(counts, 0, (size_t)2 * N * 4, stream);

    conv_weights<<<(4 * 8192 + 255) / 256, 256, 0, stream>>>(Wq, Wk, Wv, Wo, Wbuf);

    const int mb32 = (N + 31) / 32;
    gemm_qkv<<<dim3(mb32, 3), 256, 0, stream>>>(query, key, value, Wbuf,
                                                bq, bk, bv, qbuf, kvbuf, N);

    const int eblocks = (E + 255) / 256;
    hist_kernel<<<eblocks, 256, 0, stream>>>(dst, E, counts);

    const int G = (N + 256) / 256;  // ceil((N+1)/256)
    block_reduce_kernel<<<G, 256, 0, stream>>>(counts, N, bsums);
    scan_blocks_kernel<<<1, 256, 0, stream>>>(bsums, G);
    scan_write_kernel<<<G, 256, 0, stream>>>(counts, N, bsums, offsets);

    fill_kernel<<<eblocks, 256, 0, stream>>>(dst, src, E, offsets, counts + N, ssrc);
    attn_kernel<<<(N + 3) / 4, 256, 0, stream>>>(qbuf, kvbuf, offsets, ssrc, attnb, N);

    gemm_out<<<mb32, 256, 0, stream>>>(attnb, Wbuf + 3 * D_MODEL * D_MODEL, bo, out, N);
}

// Round 7
// 374.813 us; speedup vs baseline: 1.5958x; 1.0383x over previous
//
#include <hip/hip_runtime.h>
#include <hip/hip_bf16.h>
#include <cstdint>

#define D_MODEL 256
#define NHEADS 8
#define DK 32
#define LDSPAD 8
#define LDSROW (D_MODEL + LDSPAD)   // 264 bf16 per LDS row
#define LDSROWF (D_MODEL + 4)       // 260 f32 per LDS row (gemm_out epilogue)

typedef float f32x4 __attribute__((ext_vector_type(4)));
typedef __bf16 bf16x8 __attribute__((ext_vector_type(8)));

__device__ __forceinline__ unsigned short f2bf_rne(float f) {
    unsigned int u = __float_as_uint(f);
    u += 0x7FFF + ((u >> 16) & 1);
    return (unsigned short)(u >> 16);
}
__device__ __forceinline__ float bf2f(unsigned short h) {
    return __uint_as_float(((unsigned int)h) << 16);
}

// ---------------- weight fp32 -> bf16, pre-swizzled into MFMA B-fragment order ---
// Layout: for weight w, fragment block (ntile 0..15, kk 0..7): 1 KB containing
// lane-major bf16x8: elem j of lane l = W[ntile*16 + (l&15)][kk*32 + (l>>4)*8 + j].
__global__ void conv_weights(const float* __restrict__ W0, const float* __restrict__ W1,
                             const float* __restrict__ W2, const float* __restrict__ W3,
                             unsigned short* __restrict__ out) {
    int i = blockIdx.x * blockDim.x + threadIdx.x;   // 4 * 16*8*64 = 32768 threads
    if (i >= 4 * 8192) return;
    const int w    = i >> 13;
    const int rem  = i & 8191;            // (ntile*8 + kk)*64 + lane
    const int lane = rem & 63;
    const int kk   = (rem >> 6) & 7;
    const int ntile= rem >> 9;
    const int row  = ntile * 16 + (lane & 15);
    const int col  = kk * 32 + (lane >> 4) * 8;
    const float* Wsrc = (w == 0) ? W0 : (w == 1) ? W1 : (w == 2) ? W2 : W3;
    const float* sp = Wsrc + (size_t)row * D_MODEL + col;
    float4 x0 = *(const float4*)sp;
    float4 x1 = *(const float4*)(sp + 4);
    unsigned short* dp = out + (size_t)w * D_MODEL * D_MODEL + (size_t)rem * 8;
    ushort4 o0, o1;
    o0.x = f2bf_rne(x0.x); o0.y = f2bf_rne(x0.y); o0.z = f2bf_rne(x0.z); o0.w = f2bf_rne(x0.w);
    o1.x = f2bf_rne(x1.x); o1.y = f2bf_rne(x1.y); o1.z = f2bf_rne(x1.z); o1.w = f2bf_rne(x1.w);
    *(ushort4*)dp = o0;
    *(ushort4*)(dp + 4) = o1;
}

// ---------------- merged QKV GEMM: 3 GEMMs in one dispatch -----------------------
// blockIdx.y in {0,1,2} selects (A, Wslice, bias, out) for q/k/v projections.
// BM=64 rows/block (16 MFMA per kk vs 4 B-loads: amortizes B-fragment L2 latency;
// halves total B L2 traffic vs BM=32). A staged via LDS; B from pre-swizzled
// global. Epilogue transposes through LDS for 16 B/lane coalesced bf16 stores.
// MFMA 16x16x32 bf16. D: col=lane&15, row=quad*4+reg.
__global__ __launch_bounds__(256, 4) void gemm_qkv(
    const float* __restrict__ Aq, const float* __restrict__ Ak, const float* __restrict__ Av,
    const unsigned short* __restrict__ Wsw,
    const float* __restrict__ bq, const float* __restrict__ bk, const float* __restrict__ bv,
    unsigned short* __restrict__ qbuf, unsigned short* __restrict__ kvbuf, int M)
{
    __shared__ __align__(16) unsigned short smem[64 * LDSROW];

    const int which = blockIdx.y;
    const float* A = (which == 0) ? Aq : (which == 1) ? Ak : Av;
    const float* bias = (which == 0) ? bq : (which == 1) ? bk : bv;
    const unsigned short* Wb = Wsw + (size_t)which * D_MODEL * D_MODEL;
    unsigned short* outp = (which == 0) ? qbuf : kvbuf;
    const int out_stride = (which == 0) ? D_MODEL : 2 * D_MODEL;
    const int out_off    = (which == 2) ? D_MODEL : 0;

    const int lane  = threadIdx.x & 63;
    const int wave  = threadIdx.x >> 6;
    const int m0    = blockIdx.x * 64;
    const int mrow  = lane & 15;
    const int quad  = lane >> 4;

    // ---- stage A tile (64 x 256 fp32) into LDS as bf16 ----
#pragma unroll
    for (int i = 0; i < 16; ++i) {
        const int g = i * 256 + threadIdx.x;     // float4 index
        const int r = g >> 6, c4 = g & 63;
        const int grow = min(m0 + r, M - 1);
        float4 x = *(const float4*)(A + (size_t)grow * D_MODEL + c4 * 4);
        ushort4 o;
        o.x = f2bf_rne(x.x); o.y = f2bf_rne(x.y);
        o.z = f2bf_rne(x.z); o.w = f2bf_rne(x.w);
        *(ushort4*)(smem + r * LDSROW + c4 * 4) = o;
    }
    __syncthreads();

    f32x4 acc[4][4] = {};

#pragma unroll
    for (int kk = 0; kk < 8; ++kk) {
        bf16x8 bfr[4];
#pragma unroll
        for (int ni = 0; ni < 4; ++ni) {
            const int ntile = wave * 4 + ni;
            bfr[ni] = *(const bf16x8*)(Wb + ((size_t)(ntile * 8 + kk) * 64 + lane) * 8);
        }
        bf16x8 afr[4];
#pragma unroll
        for (int mi = 0; mi < 4; ++mi)
            afr[mi] = *(const bf16x8*)(smem + (mi * 16 + mrow) * LDSROW + kk * 32 + quad * 8);
#pragma unroll
        for (int mi = 0; mi < 4; ++mi)
#pragma unroll
            for (int ni = 0; ni < 4; ++ni)
                acc[mi][ni] = __builtin_amdgcn_mfma_f32_16x16x32_bf16(
                    afr[mi], bfr[ni], acc[mi][ni], 0, 0, 0);
    }

    // ---- epilogue: bias + bf16, transpose through LDS, coalesced 16B stores ----
    __syncthreads();   // all waves finished reading A-tile from smem
#pragma unroll
    for (int ni = 0; ni < 4; ++ni) {
        const int col = wave * 64 + ni * 16 + mrow;
        const float bv2 = bias[col];
#pragma unroll
        for (int mi = 0; mi < 4; ++mi)
#pragma unroll
            for (int r = 0; r < 4; ++r)
                smem[(mi * 16 + quad * 4 + r) * LDSROW + col] = f2bf_rne(acc[mi][ni][r] + bv2);
    }
    __syncthreads();
#pragma unroll
    for (int i = 0; i < 8; ++i) {
        const int g = i * 256 + threadIdx.x;     // ushort8 chunk index
        const int r = g >> 5, c8 = g & 31;
        const int grow = m0 + r;
        if (grow < M) {
            bf16x8 x = *(const bf16x8*)(smem + r * LDSROW + c8 * 8);
            *(bf16x8*)(outp + (size_t)grow * out_stride + out_off + c8 * 8) = x;
        }
    }
}

// ---------------- output GEMM: out[M,256] = attn(bf16) @ Wo^T + bo (fp32) --------
// BM=32. Epilogue transposes fp32 through LDS so stores are full-row float4
// (direct 64 B half-line stores showed 1.6x HBM write amplification).
__global__ __launch_bounds__(256, 4) void gemm_out(
    const unsigned short* __restrict__ Ab, const unsigned short* __restrict__ Wb,
    const float* __restrict__ bias, float* __restrict__ outp, int M)
{
    __shared__ __align__(16) char smem_raw[32 * LDSROWF * 4];
    unsigned short* smemA = (unsigned short*)smem_raw;   // 32 x LDSROW bf16 (staging)
    float*          smemF = (float*)smem_raw;            // 32 x LDSROWF f32 (epilogue)

    const int lane  = threadIdx.x & 63;
    const int wave  = threadIdx.x >> 6;
    const int m0    = blockIdx.x * 32;
    const int mrow  = lane & 15;
    const int quad  = lane >> 4;

    // ---- stage A tile (32 x 256 bf16) into LDS ----
#pragma unroll
    for (int i = 0; i < 4; ++i) {
        const int g = i * 256 + threadIdx.x;     // ushort8 index
        const int r = g >> 5, c8 = g & 31;
        const int grow = min(m0 + r, M - 1);
        bf16x8 x = *(const bf16x8*)(Ab + (size_t)grow * D_MODEL + c8 * 8);
        *(bf16x8*)(smemA + r * LDSROW + c8 * 8) = x;
    }
    __syncthreads();

    f32x4 acc[2][4] = {};

#pragma unroll
    for (int kk = 0; kk < 8; ++kk) {
        bf16x8 bfr[4];
#pragma unroll
        for (int ni = 0; ni < 4; ++ni) {
            const int ntile = wave * 4 + ni;
            bfr[ni] = *(const bf16x8*)(Wb + ((size_t)(ntile * 8 + kk) * 64 + lane) * 8);
        }
        bf16x8 afr[2];
#pragma unroll
        for (int mi = 0; mi < 2; ++mi)
            afr[mi] = *(const bf16x8*)(smemA + (mi * 16 + mrow) * LDSROW + kk * 32 + quad * 8);
#pragma unroll
        for (int mi = 0; mi < 2; ++mi)
#pragma unroll
            for (int ni = 0; ni < 4; ++ni)
                acc[mi][ni] = __builtin_amdgcn_mfma_f32_16x16x32_bf16(
                    afr[mi], bfr[ni], acc[mi][ni], 0, 0, 0);
    }

    // ---- epilogue: bias, transpose fp32 through LDS, full-row float4 stores ----
    __syncthreads();
#pragma unroll
    for (int ni = 0; ni < 4; ++ni) {
        const int col = wave * 64 + ni * 16 + mrow;
        const float bv2 = bias[col];
#pragma unroll
        for (int mi = 0; mi < 2; ++mi)
#pragma unroll
            for (int r = 0; r < 4; ++r)
                smemF[(mi * 16 + quad * 4 + r) * LDSROWF + col] = acc[mi][ni][r] + bv2;
    }
    __syncthreads();
#pragma unroll
    for (int i = 0; i < 8; ++i) {
        const int g = i * 256 + threadIdx.x;     // float4 chunk index
        const int r = g >> 6, c4 = g & 63;
        const int grow = m0 + r;
        if (grow < M) {
            float4 x = *(const float4*)(smemF + r * LDSROWF + c4 * 4);
            *(float4*)(outp + (size_t)grow * D_MODEL + c4 * 4) = x;
        }
    }
}

// ---------------- CSR construction ----------------
__global__ void hist_kernel(const int* __restrict__ dst, int E, int* __restrict__ counts) {
    int i = blockIdx.x * blockDim.x + threadIdx.x;
    if (i < E) atomicAdd(&counts[dst[i]], 1);
}

__global__ void block_reduce_kernel(const int* __restrict__ counts, int N,
                                    int* __restrict__ blockSums) {
    const int g = blockIdx.x * 256 + threadIdx.x;
    int v = (g < N) ? counts[g] : 0;
#pragma unroll
    for (int d = 1; d < 64; d <<= 1) v += __shfl_xor(v, d);
    __shared__ int ws[4];
    if ((threadIdx.x & 63) == 0) ws[threadIdx.x >> 6] = v;
    __syncthreads();
    if (threadIdx.x == 0) blockSums[blockIdx.x] = ws[0] + ws[1] + ws[2] + ws[3];
}

__global__ void scan_blocks_kernel(int* __restrict__ blockSums, int G) {
    __shared__ int sh[256];
    const int t = threadIdx.x;
    int v = (t < G) ? blockSums[t] : 0;
    sh[t] = v;
    __syncthreads();
#pragma unroll
    for (int off = 1; off < 256; off <<= 1) {
        int add = (t >= off) ? sh[t - off] : 0;
        __syncthreads();
        sh[t] += add;
        __syncthreads();
    }
    if (t < G) blockSums[t] = sh[t] - v;   // exclusive
}

__global__ void scan_write_kernel(const int* __restrict__ counts, int N,
                                  const int* __restrict__ blockOffsets,
                                  int* __restrict__ offsets) {
    const int g = blockIdx.x * 256 + threadIdx.x;
    const int t = threadIdx.x;
    int v = (g < N) ? counts[g] : 0;
    __shared__ int sh[256];
    sh[t] = v;
    __syncthreads();
#pragma unroll
    for (int off = 1; off < 256; off <<= 1) {
        int add = (t >= off) ? sh[t - off] : 0;
        __syncthreads();
        sh[t] += add;
        __syncthreads();
    }
    if (g <= N) offsets[g] = sh[t] - v + blockOffsets[blockIdx.x];
}

__global__ void fill_kernel(const int* __restrict__ dst, const int* __restrict__ src, int E,
                            const int* __restrict__ offsets, int* __restrict__ cursor,
                            int* __restrict__ ssrc) {
    int i = blockIdx.x * blockDim.x + threadIdx.x;
    if (i < E) {
        int d = dst[i];
        int r = atomicAdd(&cursor[d], 1);
        ssrc[offsets[d] + r] = src[i];
    }
}

// ---------------- per-node online-softmax attention ----------------
// One wave per node. Lane l owns elements 4l..4l+3 (head = l>>3).
// kv layout: row s = [K(256 bf16) | V(256 bf16)], 1 KB per node.
__global__ __launch_bounds__(256) void attn_kernel(
    const unsigned short* __restrict__ qb, const unsigned short* __restrict__ kv,
    const int* __restrict__ offsets, const int* __restrict__ ssrc,
    unsigned short* __restrict__ attn, int N)
{
    const int node = blockIdx.x * 4 + (threadIdx.x >> 6);
    if (node >= N) return;
    const int lane = threadIdx.x & 63;

    ushort4 qu = *(const ushort4*)(qb + (size_t)node * D_MODEL + 4 * lane);
    const float sc = 0.17677669529663689f;  // 1/sqrt(32)
    float qx = bf2f(qu.x) * sc, qy = bf2f(qu.y) * sc,
          qz = bf2f(qu.z) * sc, qw = bf2f(qu.w) * sc;

    float m = -INFINITY, l = 0.f;
    float ax = 0.f, ay = 0.f, az = 0.f, aw = 0.f;

    const int e0 = offsets[node], e1 = offsets[node + 1];
    int e = e0;

    for (; e + 3 < e1; e += 4) {
        int s0 = ssrc[e], s1 = ssrc[e + 1], s2 = ssrc[e + 2], s3 = ssrc[e + 3];
        const unsigned short* b0 = kv + (size_t)s0 * 512;
        const unsigned short* b1 = kv + (size_t)s1 * 512;
        const unsigned short* b2 = kv + (size_t)s2 * 512;
        const unsigned short* b3 = kv + (size_t)s3 * 512;
        ushort4 k0 = *(const ushort4*)(b0 + 4 * lane);
        ushort4 k1 = *(const ushort4*)(b1 + 4 * lane);
        ushort4 k2 = *(const ushort4*)(b2 + 4 * lane);
        ushort4 k3 = *(const ushort4*)(b3 + 4 * lane);
        ushort4 v0 = *(const ushort4*)(b0 + D_MODEL + 4 * lane);
        ushort4 v1 = *(const ushort4*)(b1 + D_MODEL + 4 * lane);
        ushort4 v2 = *(const ushort4*)(b2 + D_MODEL + 4 * lane);
        ushort4 v3 = *(const ushort4*)(b3 + D_MODEL + 4 * lane);

        float p0 = qx * bf2f(k0.x) + qy * bf2f(k0.y) + qz * bf2f(k0.z) + qw * bf2f(k0.w);
        float p1 = qx * bf2f(k1.x) + qy * bf2f(k1.y) + qz * bf2f(k1.z) + qw * bf2f(k1.w);
        float p2 = qx * bf2f(k2.x) + qy * bf2f(k2.y) + qz * bf2f(k2.z) + qw * bf2f(k2.w);
        float p3 = qx * bf2f(k3.x) + qy * bf2f(k3.y) + qz * bf2f(k3.z) + qw * bf2f(k3.w);
#pragma unroll
        for (int d = 1; d <= 4; d <<= 1) {
            p0 += __shfl_xor(p0, d);
            p1 += __shfl_xor(p1, d);
            p2 += __shfl_xor(p2, d);
            p3 += __shfl_xor(p3, d);
        }
        float mnew = fmaxf(fmaxf(fmaxf(m, p0), fmaxf(p1, p2)), p3);
        float alpha = __expf(m - mnew);     // 0 on first group (m=-inf)
        float w0 = __expf(p0 - mnew), w1 = __expf(p1 - mnew);
        float w2 = __expf(p2 - mnew), w3 = __expf(p3 - mnew);
        ax = ax * alpha + w0 * bf2f(v0.x) + w1 * bf2f(v1.x) + w2 * bf2f(v2.x) + w3 * bf2f(v3.x);
        ay = ay * alpha + w0 * bf2f(v0.y) + w1 * bf2f(v1.y) + w2 * bf2f(v2.y) + w3 * bf2f(v3.y);
        az = az * alpha + w0 * bf2f(v0.z) + w1 * bf2f(v1.z) + w2 * bf2f(v2.z) + w3 * bf2f(v3.z);
        aw = aw * alpha + w0 * bf2f(v0.w) + w1 * bf2f(v1.w) + w2 * bf2f(v2.w) + w3 * bf2f(v3.w);
        l = l * alpha + w0 + w1 + w2 + w3;
        m = mnew;
    }
    for (; e < e1; ++e) {
        int s = ssrc[e];
        const unsigned short* b = kv + (size_t)s * 512;
        ushort4 ku = *(const ushort4*)(b + 4 * lane);
        ushort4 vu = *(const ushort4*)(b + D_MODEL + 4 * lane);
        float p = qx * bf2f(ku.x) + qy * bf2f(ku.y) + qz * bf2f(ku.z) + qw * bf2f(ku.w);
        p += __shfl_xor(p, 1);
        p += __shfl_xor(p, 2);
        p += __shfl_xor(p, 4);
        float mnew  = fmaxf(m, p);
        float alpha = __expf(m - mnew);
        float w     = __expf(p - mnew);
        ax = ax * alpha + w * bf2f(vu.x);
        ay = ay * alpha + w * bf2f(vu.y);
        az = az * alpha + w * bf2f(vu.z);
        aw = aw * alpha + w * bf2f(vu.w);
        l = l * alpha + w;
        m = mnew;
    }

    const float inv = (l > 0.f) ? 1.f / l : 0.f;  // deg-0 nodes -> zeros
    ushort4 o;
    o.x = f2bf_rne(ax * inv);
    o.y = f2bf_rne(ay * inv);
    o.z = f2bf_rne(az * inv);
    o.w = f2bf_rne(aw * inv);
    *(ushort4*)(attn + (size_t)node * D_MODEL + 4 * lane) = o;
}

// ---------------- launch ----------------
extern "C" void kernel_launch(void* const* d_in, const int* in_sizes, int n_in,
                              void* d_out, int out_size, void* d_ws, size_t ws_size,
                              hipStream_t stream)
{
    const float* query = (const float*)d_in[0];
    const float* key   = (const float*)d_in[1];
    const float* value = (const float*)d_in[2];
    const int*   edges = (const int*)d_in[3];
    const float* Wq = (const float*)d_in[4];
    const float* bq = (const float*)d_in[5];
    const float* Wk = (const float*)d_in[6];
    const float* bk = (const float*)d_in[7];
    const float* Wv = (const float*)d_in[8];
    const float* bv = (const float*)d_in[9];
    const float* Wo = (const float*)d_in[10];
    const float* bo = (const float*)d_in[11];
    float* out = (float*)d_out;

    const int N = in_sizes[0] / D_MODEL;
    const int E = in_sizes[3] / 2;
    const int* dst = edges;
    const int* src = edges + E;

    char* ws = (char*)d_ws;
    size_t off = 0;
    auto alloc = [&](size_t bytes) {
        void* p = ws + off;
        off += (bytes + 255) & ~(size_t)255;
        return p;
    };
    unsigned short* qbuf  = (unsigned short*)alloc((size_t)N * D_MODEL * 2);
    unsigned short* kvbuf = (unsigned short*)alloc((size_t)N * 2 * D_MODEL * 2); // K|V interleaved
    unsigned short* attnb = (unsigned short*)alloc((size_t)N * D_MODEL * 2);
    unsigned short* Wbuf  = (unsigned short*)alloc((size_t)4 * D_MODEL * D_MODEL * 2);
    int*            counts  = (int*)alloc((size_t)2 * N * 4);   // counts + cursor contiguous
    int*            offsets = (int*)alloc((size_t)(N + 1) * 4);
    int*            ssrc    = (int*)alloc((size_t)E * 4);
    int*            bsums   = (int*)alloc((size_t)256 * 4);

    hipMemsetAsync(counts, 0, (size_t)2 * N * 4, stream);

    conv_weights<<<(4 * 8192 + 255) / 256, 256, 0, stream>>>(Wq, Wk, Wv, Wo, Wbuf);

    const int mb64 = (N + 63) / 64;
    gemm_qkv<<<dim3(mb64, 3), 256, 0, stream>>>(query, key, value, Wbuf,
                                                bq, bk, bv, qbuf, kvbuf, N);

    const int eblocks = (E + 255) / 256;
    hist_kernel<<<eblocks, 256, 0, stream>>>(dst, E, counts);

    const int G = (N + 256) / 256;  // ceil((N+1)/256)
    block_reduce_kernel<<<G, 256, 0, stream>>>(counts, N, bsums);
    scan_blocks_kernel<<<1, 256, 0, stream>>>(bsums, G);
    scan_write_kernel<<<G, 256, 0, stream>>>(counts, N, bsums, offsets);

    fill_kernel<<<eblocks, 256, 0, stream>>>(dst, src, E, offsets, counts + N, ssrc);
    attn_kernel<<<(N + 3) / 4, 256, 0, stream>>>(qbuf, kvbuf, offsets, ssrc, attnb, N);

    const int mb32 = (N + 31) / 32;
    gemm_out<<<mb32, 256, 0, stream>>>(attnb, Wbuf + 3 * D_MODEL * D_MODEL, bo, out, N);
}

// Round 8
// 357.996 us; speedup vs baseline: 1.6708x; 1.0470x over previous
//
#include <hip/hip_runtime.h>
#include <hip/hip_bf16.h>
#include <cstdint>

#define D_MODEL 256
#define NHEADS 8
#define DK 32
#define LDSPAD 8
#define LDSROW (D_MODEL + LDSPAD)   // 264 bf16 per LDS row
#define LDSROWF (D_MODEL + 4)       // 260 f32 per LDS row (gemm_out epilogue)
#define PBLK 170                    // persistent x-blocks (170*3=510 <= 512 = 2/CU)

typedef float f32x4 __attribute__((ext_vector_type(4)));
typedef __bf16 bf16x8 __attribute__((ext_vector_type(8)));

__device__ __forceinline__ unsigned short f2bf_rne(float f) {
    unsigned int u = __float_as_uint(f);
    u += 0x7FFF + ((u >> 16) & 1);
    return (unsigned short)(u >> 16);
}
__device__ __forceinline__ float bf2f(unsigned short h) {
    return __uint_as_float(((unsigned int)h) << 16);
}

// ---------------- weight fp32 -> bf16, pre-swizzled into MFMA B-fragment order ---
// Layout: for weight w, fragment block (ntile 0..15, kk 0..7): 1 KB containing
// lane-major bf16x8: elem j of lane l = W[ntile*16 + (l&15)][kk*32 + (l>>4)*8 + j].
__global__ void conv_weights(const float* __restrict__ W0, const float* __restrict__ W1,
                             const float* __restrict__ W2, const float* __restrict__ W3,
                             unsigned short* __restrict__ out) {
    int i = blockIdx.x * blockDim.x + threadIdx.x;   // 4 * 16*8*64 = 32768 threads
    if (i >= 4 * 8192) return;
    const int w    = i >> 13;
    const int rem  = i & 8191;            // (ntile*8 + kk)*64 + lane
    const int lane = rem & 63;
    const int kk   = (rem >> 6) & 7;
    const int ntile= rem >> 9;
    const int row  = ntile * 16 + (lane & 15);
    const int col  = kk * 32 + (lane >> 4) * 8;
    const float* Wsrc = (w == 0) ? W0 : (w == 1) ? W1 : (w == 2) ? W2 : W3;
    const float* sp = Wsrc + (size_t)row * D_MODEL + col;
    float4 x0 = *(const float4*)sp;
    float4 x1 = *(const float4*)(sp + 4);
    unsigned short* dp = out + (size_t)w * D_MODEL * D_MODEL + (size_t)rem * 8;
    ushort4 o0, o1;
    o0.x = f2bf_rne(x0.x); o0.y = f2bf_rne(x0.y); o0.z = f2bf_rne(x0.z); o0.w = f2bf_rne(x0.w);
    o1.x = f2bf_rne(x1.x); o1.y = f2bf_rne(x1.y); o1.z = f2bf_rne(x1.z); o1.w = f2bf_rne(x1.w);
    *(ushort4*)dp = o0;
    *(ushort4*)(dp + 4) = o1;
}

// ---------------- persistent-B merged QKV GEMM -----------------------------------
// blockIdx.y selects q/k/v. Each block loads its wave's B-fragments (4 ntiles x
// 8 kk = 32 KB = 128 VGPRs) ONCE, then loops over ~9 m-tiles (BM=32): the K-loop
// is pure LDS-read + MFMA (no global loads -> no per-iteration L2 latency).
// __launch_bounds__(256,2): 256-VGPR budget for the resident B fragments.
__global__ __launch_bounds__(256, 2) void gemm_qkv(
    const float* __restrict__ Aq, const float* __restrict__ Ak, const float* __restrict__ Av,
    const unsigned short* __restrict__ Wsw,
    const float* __restrict__ bq, const float* __restrict__ bk, const float* __restrict__ bv,
    unsigned short* __restrict__ qbuf, unsigned short* __restrict__ kvbuf,
    int M, int mtiles)
{
    __shared__ __align__(16) unsigned short smem[32 * LDSROW];

    const int which = blockIdx.y;
    const float* A = (which == 0) ? Aq : (which == 1) ? Ak : Av;
    const float* bias = (which == 0) ? bq : (which == 1) ? bk : bv;
    const unsigned short* Wb = Wsw + (size_t)which * D_MODEL * D_MODEL;
    unsigned short* outp = (which == 0) ? qbuf : kvbuf;
    const int out_stride = (which == 0) ? D_MODEL : 2 * D_MODEL;
    const int out_off    = (which == 2) ? D_MODEL : 0;

    const int lane  = threadIdx.x & 63;
    const int wave  = threadIdx.x >> 6;
    const int mrow  = lane & 15;
    const int quad  = lane >> 4;

    // ---- load B fragments once: [ni][kk], 128 VGPRs ----
    bf16x8 bfr[4][8];
#pragma unroll
    for (int ni = 0; ni < 4; ++ni)
#pragma unroll
        for (int kk = 0; kk < 8; ++kk)
            bfr[ni][kk] = *(const bf16x8*)(Wb + ((size_t)((wave * 4 + ni) * 8 + kk) * 64 + lane) * 8);

    // ---- per-wave column bias (reused every tile) ----
    float bcol[4];
#pragma unroll
    for (int ni = 0; ni < 4; ++ni) bcol[ni] = bias[wave * 64 + ni * 16 + mrow];

    for (int t = blockIdx.x; t < mtiles; t += PBLK) {
        const int m0 = t * 32;

        // ---- stage A tile (32 x 256 fp32) into LDS as bf16 ----
#pragma unroll
        for (int i = 0; i < 8; ++i) {
            const int g = i * 256 + threadIdx.x;     // float4 index
            const int r = g >> 6, c4 = g & 63;
            const int grow = min(m0 + r, M - 1);
            float4 x = *(const float4*)(A + (size_t)grow * D_MODEL + c4 * 4);
            ushort4 o;
            o.x = f2bf_rne(x.x); o.y = f2bf_rne(x.y);
            o.z = f2bf_rne(x.z); o.w = f2bf_rne(x.w);
            *(ushort4*)(smem + r * LDSROW + c4 * 4) = o;
        }
        __syncthreads();

        f32x4 acc[2][4] = {};
#pragma unroll
        for (int kk = 0; kk < 8; ++kk) {
            bf16x8 afr[2];
#pragma unroll
            for (int mi = 0; mi < 2; ++mi)
                afr[mi] = *(const bf16x8*)(smem + (mi * 16 + mrow) * LDSROW + kk * 32 + quad * 8);
#pragma unroll
            for (int mi = 0; mi < 2; ++mi)
#pragma unroll
                for (int ni = 0; ni < 4; ++ni)
                    acc[mi][ni] = __builtin_amdgcn_mfma_f32_16x16x32_bf16(
                        afr[mi], bfr[ni][kk], acc[mi][ni], 0, 0, 0);
        }

        // ---- epilogue: bias + bf16, transpose through LDS, coalesced stores ----
        __syncthreads();
#pragma unroll
        for (int ni = 0; ni < 4; ++ni) {
            const int col = wave * 64 + ni * 16 + mrow;
#pragma unroll
            for (int mi = 0; mi < 2; ++mi)
#pragma unroll
                for (int r = 0; r < 4; ++r)
                    smem[(mi * 16 + quad * 4 + r) * LDSROW + col] =
                        f2bf_rne(acc[mi][ni][r] + bcol[ni]);
        }
        __syncthreads();
#pragma unroll
        for (int i = 0; i < 4; ++i) {
            const int g = i * 256 + threadIdx.x;     // ushort8 chunk index
            const int r = g >> 5, c8 = g & 31;
            const int grow = m0 + r;
            if (grow < M) {
                bf16x8 x = *(const bf16x8*)(smem + r * LDSROW + c8 * 8);
                *(bf16x8*)(outp + (size_t)grow * out_stride + out_off + c8 * 8) = x;
            }
        }
        __syncthreads();   // stores read smem; next tile's staging overwrites it
    }
}

// ---------------- persistent-B output GEMM: out = attn(bf16) @ Wo^T + bo (fp32) --
__global__ __launch_bounds__(256, 2) void gemm_out(
    const unsigned short* __restrict__ Ab, const unsigned short* __restrict__ Wb,
    const float* __restrict__ bias, float* __restrict__ outp, int M, int mtiles)
{
    __shared__ __align__(16) char smem_raw[32 * LDSROWF * 4];
    unsigned short* smemA = (unsigned short*)smem_raw;   // 32 x LDSROW bf16 (staging)
    float*          smemF = (float*)smem_raw;            // 32 x LDSROWF f32 (epilogue)

    const int lane  = threadIdx.x & 63;
    const int wave  = threadIdx.x >> 6;
    const int mrow  = lane & 15;
    const int quad  = lane >> 4;

    bf16x8 bfr[4][8];
#pragma unroll
    for (int ni = 0; ni < 4; ++ni)
#pragma unroll
        for (int kk = 0; kk < 8; ++kk)
            bfr[ni][kk] = *(const bf16x8*)(Wb + ((size_t)((wave * 4 + ni) * 8 + kk) * 64 + lane) * 8);

    float bcol[4];
#pragma unroll
    for (int ni = 0; ni < 4; ++ni) bcol[ni] = bias[wave * 64 + ni * 16 + mrow];

    for (int t = blockIdx.x; t < mtiles; t += 3 * PBLK) {
        const int m0 = t * 32;

        // ---- stage A tile (32 x 256 bf16) into LDS ----
#pragma unroll
        for (int i = 0; i < 4; ++i) {
            const int g = i * 256 + threadIdx.x;     // ushort8 index
            const int r = g >> 5, c8 = g & 31;
            const int grow = min(m0 + r, M - 1);
            bf16x8 x = *(const bf16x8*)(Ab + (size_t)grow * D_MODEL + c8 * 8);
            *(bf16x8*)(smemA + r * LDSROW + c8 * 8) = x;
        }
        __syncthreads();

        f32x4 acc[2][4] = {};
#pragma unroll
        for (int kk = 0; kk < 8; ++kk) {
            bf16x8 afr[2];
#pragma unroll
            for (int mi = 0; mi < 2; ++mi)
                afr[mi] = *(const bf16x8*)(smemA + (mi * 16 + mrow) * LDSROW + kk * 32 + quad * 8);
#pragma unroll
            for (int mi = 0; mi < 2; ++mi)
#pragma unroll
                for (int ni = 0; ni < 4; ++ni)
                    acc[mi][ni] = __builtin_amdgcn_mfma_f32_16x16x32_bf16(
                        afr[mi], bfr[ni][kk], acc[mi][ni], 0, 0, 0);
        }

        // ---- epilogue: bias, transpose fp32 through LDS, float4 stores ----
        __syncthreads();
#pragma unroll
        for (int ni = 0; ni < 4; ++ni) {
            const int col = wave * 64 + ni * 16 + mrow;
#pragma unroll
            for (int mi = 0; mi < 2; ++mi)
#pragma unroll
                for (int r = 0; r < 4; ++r)
                    smemF[(mi * 16 + quad * 4 + r) * LDSROWF + col] = acc[mi][ni][r] + bcol[ni];
        }
        __syncthreads();
#pragma unroll
        for (int i = 0; i < 8; ++i) {
            const int g = i * 256 + threadIdx.x;     // float4 chunk index
            const int r = g >> 6, c4 = g & 63;
            const int grow = m0 + r;
            if (grow < M) {
                float4 x = *(const float4*)(smemF + r * LDSROWF + c4 * 4);
                *(float4*)(outp + (size_t)grow * D_MODEL + c4 * 4) = x;
            }
        }
        __syncthreads();
    }
}

// ---------------- CSR construction ----------------
__global__ void hist_kernel(const int* __restrict__ dst, int E, int* __restrict__ counts) {
    int i = blockIdx.x * blockDim.x + threadIdx.x;
    if (i < E) atomicAdd(&counts[dst[i]], 1);
}

__global__ void block_reduce_kernel(const int* __restrict__ counts, int N,
                                    int* __restrict__ blockSums) {
    const int g = blockIdx.x * 256 + threadIdx.x;
    int v = (g < N) ? counts[g] : 0;
#pragma unroll
    for (int d = 1; d < 64; d <<= 1) v += __shfl_xor(v, d);
    __shared__ int ws[4];
    if ((threadIdx.x & 63) == 0) ws[threadIdx.x >> 6] = v;
    __syncthreads();
    if (threadIdx.x == 0) blockSums[blockIdx.x] = ws[0] + ws[1] + ws[2] + ws[3];
}

__global__ void scan_blocks_kernel(int* __restrict__ blockSums, int G) {
    __shared__ int sh[256];
    const int t = threadIdx.x;
    int v = (t < G) ? blockSums[t] : 0;
    sh[t] = v;
    __syncthreads();
#pragma unroll
    for (int off = 1; off < 256; off <<= 1) {
        int add = (t >= off) ? sh[t - off] : 0;
        __syncthreads();
        sh[t] += add;
        __syncthreads();
    }
    if (t < G) blockSums[t] = sh[t] - v;   // exclusive
}

__global__ void scan_write_kernel(const int* __restrict__ counts, int N,
                                  const int* __restrict__ blockOffsets,
                                  int* __restrict__ offsets) {
    const int g = blockIdx.x * 256 + threadIdx.x;
    const int t = threadIdx.x;
    int v = (g < N) ? counts[g] : 0;
    __shared__ int sh[256];
    sh[t] = v;
    __syncthreads();
#pragma unroll
    for (int off = 1; off < 256; off <<= 1) {
        int add = (t >= off) ? sh[t - off] : 0;
        __syncthreads();
        sh[t] += add;
        __syncthreads();
    }
    if (g <= N) offsets[g] = sh[t] - v + blockOffsets[blockIdx.x];
}

__global__ void fill_kernel(const int* __restrict__ dst, const int* __restrict__ src, int E,
                            const int* __restrict__ offsets, int* __restrict__ cursor,
                            int* __restrict__ ssrc) {
    int i = blockIdx.x * blockDim.x + threadIdx.x;
    if (i < E) {
        int d = dst[i];
        int r = atomicAdd(&cursor[d], 1);
        ssrc[offsets[d] + r] = src[i];
    }
}

// ---------------- per-node online-softmax attention ----------------
// One wave per node. Lane l owns elements 4l..4l+3 (head = l>>3).
// kv layout: row s = [K(256 bf16) | V(256 bf16)], 1 KB per node.
__global__ __launch_bounds__(256) void attn_kernel(
    const unsigned short* __restrict__ qb, const unsigned short* __restrict__ kv,
    const int* __restrict__ offsets, const int* __restrict__ ssrc,
    unsigned short* __restrict__ attn, int N)
{
    const int node = blockIdx.x * 4 + (threadIdx.x >> 6);
    if (node >= N) return;
    const int lane = threadIdx.x & 63;

    ushort4 qu = *(const ushort4*)(qb + (size_t)node * D_MODEL + 4 * lane);
    const float sc = 0.17677669529663689f;  // 1/sqrt(32)
    float qx = bf2f(qu.x) * sc, qy = bf2f(qu.y) * sc,
          qz = bf2f(qu.z) * sc, qw = bf2f(qu.w) * sc;

    float m = -INFINITY, l = 0.f;
    float ax = 0.f, ay = 0.f, az = 0.f, aw = 0.f;

    const int e0 = offsets[node], e1 = offsets[node + 1];
    int e = e0;

    for (; e + 3 < e1; e += 4) {
        int s0 = ssrc[e], s1 = ssrc[e + 1], s2 = ssrc[e + 2], s3 = ssrc[e + 3];
        const unsigned short* b0 = kv + (size_t)s0 * 512;
        const unsigned short* b1 = kv + (size_t)s1 * 512;
        const unsigned short* b2 = kv + (size_t)s2 * 512;
        const unsigned short* b3 = kv + (size_t)s3 * 512;
        ushort4 k0 = *(const ushort4*)(b0 + 4 * lane);
        ushort4 k1 = *(const ushort4*)(b1 + 4 * lane);
        ushort4 k2 = *(const ushort4*)(b2 + 4 * lane);
        ushort4 k3 = *(const ushort4*)(b3 + 4 * lane);
        ushort4 v0 = *(const ushort4*)(b0 + D_MODEL + 4 * lane);
        ushort4 v1 = *(const ushort4*)(b1 + D_MODEL + 4 * lane);
        ushort4 v2 = *(const ushort4*)(b2 + D_MODEL + 4 * lane);
        ushort4 v3 = *(const ushort4*)(b3 + D_MODEL + 4 * lane);

        float p0 = qx * bf2f(k0.x) + qy * bf2f(k0.y) + qz * bf2f(k0.z) + qw * bf2f(k0.w);
        float p1 = qx * bf2f(k1.x) + qy * bf2f(k1.y) + qz * bf2f(k1.z) + qw * bf2f(k1.w);
        float p2 = qx * bf2f(k2.x) + qy * bf2f(k2.y) + qz * bf2f(k2.z) + qw * bf2f(k2.w);
        float p3 = qx * bf2f(k3.x) + qy * bf2f(k3.y) + qz * bf2f(k3.z) + qw * bf2f(k3.w);
#pragma unroll
        for (int d = 1; d <= 4; d <<= 1) {
            p0 += __shfl_xor(p0, d);
            p1 += __shfl_xor(p1, d);
            p2 += __shfl_xor(p2, d);
            p3 += __shfl_xor(p3, d);
        }
        float mnew = fmaxf(fmaxf(fmaxf(m, p0), fmaxf(p1, p2)), p3);
        float alpha = __expf(m - mnew);     // 0 on first group (m=-inf)
        float w0 = __expf(p0 - mnew), w1 = __expf(p1 - mnew);
        float w2 = __expf(p2 - mnew), w3 = __expf(p3 - mnew);
        ax = ax * alpha + w0 * bf2f(v0.x) + w1 * bf2f(v1.x) + w2 * bf2f(v2.x) + w3 * bf2f(v3.x);
        ay = ay * alpha + w0 * bf2f(v0.y) + w1 * bf2f(v1.y) + w2 * bf2f(v2.y) + w3 * bf2f(v3.y);
        az = az * alpha + w0 * bf2f(v0.z) + w1 * bf2f(v1.z) + w2 * bf2f(v2.z) + w3 * bf2f(v3.z);
        aw = aw * alpha + w0 * bf2f(v0.w) + w1 * bf2f(v1.w) + w2 * bf2f(v2.w) + w3 * bf2f(v3.w);
        l = l * alpha + w0 + w1 + w2 + w3;
        m = mnew;
    }
    for (; e < e1; ++e) {
        int s = ssrc[e];
        const unsigned short* b = kv + (size_t)s * 512;
        ushort4 ku = *(const ushort4*)(b + 4 * lane);
        ushort4 vu = *(const ushort4*)(b + D_MODEL + 4 * lane);
        float p = qx * bf2f(ku.x) + qy * bf2f(ku.y) + qz * bf2f(ku.z) + qw * bf2f(ku.w);
        p += __shfl_xor(p, 1);
        p += __shfl_xor(p, 2);
        p += __shfl_xor(p, 4);
        float mnew  = fmaxf(m, p);
        float alpha = __expf(m - mnew);
        float w     = __expf(p - mnew);
        ax = ax * alpha + w * bf2f(vu.x);
        ay = ay * alpha + w * bf2f(vu.y);
        az = az * alpha + w * bf2f(vu.z);
        aw = aw * alpha + w * bf2f(vu.w);
        l = l * alpha + w;
        m = mnew;
    }

    const float inv = (l > 0.f) ? 1.f / l : 0.f;  // deg-0 nodes -> zeros
    ushort4 o;
    o.x = f2bf_rne(ax * inv);
    o.y = f2bf_rne(ay * inv);
    o.z = f2bf_rne(az * inv);
    o.w = f2bf_rne(aw * inv);
    *(ushort4*)(attn + (size_t)node * D_MODEL + 4 * lane) = o;
}

// ---------------- launch ----------------
extern "C" void kernel_launch(void* const* d_in, const int* in_sizes, int n_in,
                              void* d_out, int out_size, void* d_ws, size_t ws_size,
                              hipStream_t stream)
{
    const float* query = (const float*)d_in[0];
    const float* key   = (const float*)d_in[1];
    const float* value = (const float*)d_in[2];
    const int*   edges = (const int*)d_in[3];
    const float* Wq = (const float*)d_in[4];
    const float* bq = (const float*)d_in[5];
    const float* Wk = (const float*)d_in[6];
    const float* bk = (const float*)d_in[7];
    const float* Wv = (const float*)d_in[8];
    const float* bv = (const float*)d_in[9];
    const float* Wo = (const float*)d_in[10];
    const float* bo = (const float*)d_in[11];
    float* out = (float*)d_out;

    const int N = in_sizes[0] / D_MODEL;
    const int E = in_sizes[3] / 2;
    const int* dst = edges;
    const int* src = edges + E;

    char* ws = (char*)d_ws;
    size_t off = 0;
    auto alloc = [&](size_t bytes) {
        void* p = ws + off;
        off += (bytes + 255) & ~(size_t)255;
        return p;
    };
    unsigned short* qbuf  = (unsigned short*)alloc((size_t)N * D_MODEL * 2);
    unsigned short* kvbuf = (unsigned short*)alloc((size_t)N * 2 * D_MODEL * 2); // K|V interleaved
    unsigned short* attnb = (unsigned short*)alloc((size_t)N * D_MODEL * 2);
    unsigned short* Wbuf  = (unsigned short*)alloc((size_t)4 * D_MODEL * D_MODEL * 2);
    int*            counts  = (int*)alloc((size_t)2 * N * 4);   // counts + cursor contiguous
    int*            offsets = (int*)alloc((size_t)(N + 1) * 4);
    int*            ssrc    = (int*)alloc((size_t)E * 4);
    int*            bsums   = (int*)alloc((size_t)256 * 4);

    hipMemsetAsync(counts, 0, (size_t)2 * N * 4, stream);

    conv_weights<<<(4 * 8192 + 255) / 256, 256, 0, stream>>>(Wq, Wk, Wv, Wo, Wbuf);

    const int mtiles = (N + 31) / 32;
    gemm_qkv<<<dim3(PBLK, 3), 256, 0, stream>>>(query, key, value, Wbuf,
                                                bq, bk, bv, qbuf, kvbuf, N, mtiles);

    const int eblocks = (E + 255) / 256;
    hist_kernel<<<eblocks, 256, 0, stream>>>(dst, E, counts);

    const int G = (N + 256) / 256;  // ceil((N+1)/256)
    block_reduce_kernel<<<G, 256, 0, stream>>>(counts, N, bsums);
    scan_blocks_kernel<<<1, 256, 0, stream>>>(bsums, G);
    scan_write_kernel<<<G, 256, 0, stream>>>(counts, N, bsums, offsets);

    fill_kernel<<<eblocks, 256, 0, stream>>>(dst, src, E, offsets, counts + N, ssrc);
    attn_kernel<<<(N + 3) / 4, 256, 0, stream>>>(qbuf, kvbuf, offsets, ssrc, attnb, N);

    gemm_out<<<3 * PBLK, 256, 0, stream>>>(attnb, Wbuf + 3 * D_MODEL * D_MODEL, bo, out, N, mtiles);
}